// Round 10
// baseline (636.427 us; speedup 1.0000x reference)
//
#include <hip/hip_runtime.h>
#include <math.h>

#define NN 50000
#define NE 400000
#define NB ((NN + 255) / 256)   // 196 scan blocks

typedef __attribute__((ext_vector_type(8))) short bf16x8;
typedef __attribute__((ext_vector_type(4))) float f32x4;
#define AS1 __attribute__((address_space(1)))
#define AS3 __attribute__((address_space(3)))

__device__ __forceinline__ float lrelu(float x){ return x > 0.0f ? x : 0.01f*x; }
__device__ __forceinline__ float eluf(float x){ return x > 0.0f ? x : __expf(x)-1.0f; }
__device__ __forceinline__ float bf2f(unsigned short u){
  union{unsigned i; float f;} v; v.i = ((unsigned)u)<<16; return v.f;
}
__device__ __forceinline__ unsigned short f2bf(float x){
  union{float f; unsigned i;} v; v.f = x;
  unsigned r = v.i + 0x7FFFu + ((v.i>>16)&1u);
  return (unsigned short)(r>>16);
}
__device__ __forceinline__ unsigned pack2(float a, float b){
  return (unsigned)f2bf(a) | ((unsigned)f2bf(b)<<16);
}
__device__ __forceinline__ float lo16(unsigned u){ return bf2f((unsigned short)(u & 0xffffu)); }
__device__ __forceinline__ float hi16(unsigned u){ return bf2f((unsigned short)(u >> 16)); }

// ---------------- diagnostic ----------------
__global__ void k_diag(float* out, float val){ out[0] = val; }

// ---------------- fp32 -> bf16 convert ----------------
__global__ void k_cvt(const float* __restrict__ in, unsigned short* __restrict__ o, int n){
  int i = (blockIdx.x*256 + threadIdx.x)*4;
  if(i + 3 < n){
    float4 v = *(const float4*)(in + i);
    uint2 p; p.x = pack2(v.x, v.y); p.y = pack2(v.z, v.w);
    *(uint2*)(o + i) = p;
  } else {
    for(int k = i; k < n; k++) o[k] = f2bf(in[k]);
  }
}

__global__ void k_cvt3(const float* __restrict__ s0, const float* __restrict__ s1,
    const float* __restrict__ s2, unsigned short* __restrict__ d0,
    unsigned short* __restrict__ d1, unsigned short* __restrict__ d2, int n){
  const float* in = (blockIdx.y == 0) ? s0 : (blockIdx.y == 1) ? s1 : s2;
  unsigned short* o = (blockIdx.y == 0) ? d0 : (blockIdx.y == 1) ? d1 : d2;
  int i = (blockIdx.x*256 + threadIdx.x)*4;
  if(i + 3 < n){
    float4 v = *(const float4*)(in + i);
    uint2 p; p.x = pack2(v.x, v.y); p.y = pack2(v.z, v.w);
    *(uint2*)(o + i) = p;
  } else {
    for(int k = i; k < n; k++) o[k] = f2bf(in[k]);
  }
}

__global__ void k_cvt2(const float* __restrict__ s0, const float* __restrict__ s1,
    unsigned short* __restrict__ d0, unsigned short* __restrict__ d1, int n){
  const float* in = (blockIdx.y == 0) ? s0 : s1;
  unsigned short* o = (blockIdx.y == 0) ? d0 : d1;
  int i = (blockIdx.x*256 + threadIdx.x)*4;
  if(i + 3 < n){
    float4 v = *(const float4*)(in + i);
    uint2 p; p.x = pack2(v.x, v.y); p.y = pack2(v.z, v.w);
    *(uint2*)(o + i) = p;
  } else {
    for(int k = i; k < n; k++) o[k] = f2bf(in[k]);
  }
}

// ---------------- all folds in one launch ----------------
__global__ void k_foldAll(const float* __restrict__ W0, const float* __restrict__ al0, const float* __restrict__ ar0,
    const float* __restrict__ W1, const float* __restrict__ al1, const float* __restrict__ ar1,
    const float* __restrict__ Wf, const float* __restrict__ alf, const float* __restrict__ arf,
    float* __restrict__ fl0, float* __restrict__ fr0, float* __restrict__ fl1, float* __restrict__ fr1,
    float* __restrict__ flF, float* __restrict__ frF){
  int b = blockIdx.x, d = threadIdx.x;
  const float *W, *al, *ar; float *fl, *fr; int K, h;
  if(b < 4){ W=W0; al=al0; ar=ar0; fl=fl0; fr=fr0; K=64; h=b; }
  else if(b < 8){ W=W1; al=al1; ar=ar1; fl=fl1; fr=fr1; K=64; h=b-4; }
  else { W=Wf; al=alf; ar=arf; fl=flF; fr=frF; K=121; h=b-8; }
  float sl = 0.f, sr = 0.f;
  const float* wb = W + ((size_t)h*K)*256 + d;
  for(int k = 0; k < K; k++){
    float w = wb[(size_t)k*256];
    sl += al[h*K + k]*w;
    sr += ar[h*K + k]*w;
  }
  fl[h*256 + d] = sl;
  fr[h*256 + d] = sr;
}

// ---------------- CSR build ----------------
__global__ void k_count(const int* __restrict__ dst, int* __restrict__ cnt, int E){
  int e = blockIdx.x * 256 + threadIdx.x;
  if(e < E) atomicAdd(&cnt[dst[e]], 1);
}

__global__ void k_scanA(const int* __restrict__ cnt, int* __restrict__ row_ptr,
    int* __restrict__ bsum, int N){
  __shared__ int sh[256];
  int t = threadIdx.x;
  int i = blockIdx.x*256 + t;
  int v = (i < N) ? cnt[i] : 0;
  sh[t] = v;
  __syncthreads();
  for(int off = 1; off < 256; off <<= 1){
    int u = (t >= off) ? sh[t - off] : 0;
    __syncthreads();
    sh[t] += u;
    __syncthreads();
  }
  if(i < N) row_ptr[i] = sh[t] - v;
  if(t == 255) bsum[blockIdx.x] = sh[255];
}

__global__ void k_scanB(const int* __restrict__ bsum, int* __restrict__ boff, int nb){
  __shared__ int sh[256];
  int t = threadIdx.x;
  int v = (t < nb) ? bsum[t] : 0;
  sh[t] = v;
  __syncthreads();
  for(int off = 1; off < 256; off <<= 1){
    int u = (t >= off) ? sh[t - off] : 0;
    __syncthreads();
    sh[t] += u;
    __syncthreads();
  }
  if(t < nb) boff[t] = sh[t] - v;
  if(t == 255) boff[nb] = sh[255];
}

__global__ void k_scanC(int* __restrict__ row_ptr, const int* __restrict__ boff, int N, int nb){
  int i = blockIdx.x*256 + threadIdx.x;
  if(i < N) row_ptr[i] += boff[blockIdx.x];
  if(i == 0) row_ptr[N] = boff[nb];
}

// scatter: also record the dst node per CSR position (for CSR-ordered edge kernels)
__global__ void k_scatter(const int* __restrict__ src, const int* __restrict__ dst,
    const int* __restrict__ row_ptr, int* __restrict__ cur,
    int* __restrict__ col_src, int* __restrict__ col_dst, int E){
  int e = blockIdx.x * 256 + threadIdx.x;
  if(e < E){
    int d = dst[e];
    int pos = row_ptr[d] + atomicAdd(&cur[d], 1);
    col_src[pos] = src[e];
    col_dst[pos] = d;
  }
}

// ---------------- edge-exp precompute (CSR order): ex[p][h] = exp(lrelu(a1[col_dst[p],h]+a2[col_src[p],h]))
template<int S>
__global__ __launch_bounds__(256) void k_eexp(const int* __restrict__ col_src, const int* __restrict__ col_dst,
    const float* __restrict__ a1, const float* __restrict__ a2, float* __restrict__ ex){
  int p = blockIdx.x*256 + threadIdx.x;
  if(p >= NE) return;
  int s = col_src[p], d = col_dst[p];
  if(S == 4){
    float4 v1 = *(const float4*)(a1 + (size_t)d*4);
    float4 v2 = *(const float4*)(a2 + (size_t)s*4);
    float4 o;
    o.x = __expf(lrelu(v1.x + v2.x));
    o.y = __expf(lrelu(v1.y + v2.y));
    o.z = __expf(lrelu(v1.z + v2.z));
    o.w = __expf(lrelu(v1.w + v2.w));
    *(float4*)(ex + (size_t)p*4) = o;
  } else {
    float4 l1 = *(const float4*)(a1 + (size_t)d*8);
    float2 h1 = *(const float2*)(a1 + (size_t)d*8 + 4);
    float4 l2 = *(const float4*)(a2 + (size_t)s*8);
    float2 h2 = *(const float2*)(a2 + (size_t)s*8 + 4);
    float4 o;
    o.x = __expf(lrelu(l1.x + l2.x));
    o.y = __expf(lrelu(l1.y + l2.y));
    o.z = __expf(lrelu(l1.z + l2.z));
    o.w = __expf(lrelu(l1.w + l2.w));
    float2 o2;
    o2.x = __expf(lrelu(h1.x + h2.x));
    o2.y = __expf(lrelu(h1.y + h2.y));
    *(float4*)(ex + (size_t)p*8) = o;
    *(float2*)(ex + (size_t)p*8 + 4) = o2;
  }
}

// ---------------- bf16 MFMA GEMM (128x128 tile, BK=32, 4 waves of 64x64) ----------------
__global__ __launch_bounds__(256) void k_gemm16(const unsigned short* __restrict__ X,
    const unsigned short* __restrict__ W, unsigned short* __restrict__ out,
    int N, int Kout, int ostride){
  __shared__ unsigned short sA[4096];
  __shared__ unsigned short sB[4096];
  int tid = threadIdx.x;
  int l = tid & 63, w = tid >> 6;
  int wm = w >> 1, wn = w & 1;
  int row0 = blockIdx.x*128, col0 = blockIdx.y*128;

  f32x4 acc[4][4];
  #pragma unroll
  for(int i=0;i<4;i++)
    #pragma unroll
    for(int j=0;j<4;j++) acc[i][j] = (f32x4){0.f,0.f,0.f,0.f};

  int grA0 = row0 + l;        if(grA0 >= N) grA0 = 0;
  int grA1 = row0 + 64 + l;   if(grA1 >= N) grA1 = 0;
  int gcB0 = col0 + l;        if(gcB0 >= Kout) gcB0 = 0;
  int gcB1 = col0 + 64 + l;   if(gcB1 >= Kout) gcB1 = 0;
  const unsigned short* pa0 = X + (size_t)grA0*256 + w*8;
  const unsigned short* pa1 = X + (size_t)grA1*256 + w*8;
  const unsigned short* pb0 = W + (size_t)gcB0*256 + w*8;
  const unsigned short* pb1 = W + (size_t)gcB1*256 + w*8;

  AS3 unsigned short* a3A = (AS3 unsigned short*)sA;
  AS3 unsigned short* a3B = (AS3 unsigned short*)sB;

  for(int kt = 0; kt < 256; kt += 32){
    __builtin_amdgcn_global_load_lds((const AS1 void*)(pa0 + kt), (AS3 void*)(a3A + w*1024),       16, 0, 0);
    __builtin_amdgcn_global_load_lds((const AS1 void*)(pa1 + kt), (AS3 void*)(a3A + w*1024 + 512), 16, 0, 0);
    __builtin_amdgcn_global_load_lds((const AS1 void*)(pb0 + kt), (AS3 void*)(a3B + w*1024),       16, 0, 0);
    __builtin_amdgcn_global_load_lds((const AS1 void*)(pb1 + kt), (AS3 void*)(a3B + w*1024 + 512), 16, 0, 0);
    __syncthreads();
    bf16x8 af[4], bfr[4];
    #pragma unroll
    for(int f=0; f<4; f++){
      af[f]  = *(const bf16x8*)(sA + (l>>4)*1024 + (wm*64 + f*16 + (l&15))*8);
      bfr[f] = *(const bf16x8*)(sB + (l>>4)*1024 + (wn*64 + f*16 + (l&15))*8);
    }
    #pragma unroll
    for(int i=0;i<4;i++)
      #pragma unroll
      for(int j=0;j<4;j++)
        acc[i][j] = __builtin_amdgcn_mfma_f32_16x16x32_bf16(af[i], bfr[j], acc[i][j], 0, 0, 0);
    __syncthreads();
  }

  #pragma unroll
  for(int i=0;i<4;i++){
    int rbase = row0 + wm*64 + i*16 + (l>>4)*4;
    #pragma unroll
    for(int j=0;j<4;j++){
      int c = col0 + wn*64 + j*16 + (l&15);
      if(c < Kout){
        #pragma unroll
        for(int q=0;q<4;q++){
          int r = rbase + q;
          if(r < N) out[(size_t)r*ostride + c] = f2bf(acc[i][j][q]);
        }
      }
    }
  }
}

// ---------------- final GEMM, one head per block, BK=64; fp32 atomic mean epilogue ----------------
__global__ __launch_bounds__(256) void k_gemmFh(const unsigned short* __restrict__ aggX,
    const unsigned short* __restrict__ xin, const unsigned short* __restrict__ wf,
    const unsigned short* __restrict__ rf, float* __restrict__ outp, int M){
  __shared__ unsigned short sA[8192];   // [slot 8][row 128][8]
  __shared__ unsigned short sB[8192];
  int tid = threadIdx.x;
  int l = tid & 63, w = tid >> 6;
  int wm = w >> 1, wn = w & 1;
  int h = blockIdx.y;
  int row0 = blockIdx.x*128;
  int rA0 = row0 + l;      if(rA0 >= M) rA0 = 0;
  int rA1 = row0 + 64 + l; if(rA1 >= M) rA1 = 0;
  int cB1 = 64 + l; if(cB1 > 120) cB1 = 120;

  AS3 unsigned short* a3A = (AS3 unsigned short*)sA;
  AS3 unsigned short* a3B = (AS3 unsigned short*)sB;

  f32x4 acc[4][4];
  #pragma unroll
  for(int i=0;i<4;i++)
    #pragma unroll
    for(int j=0;j<4;j++) acc[i][j] = (f32x4){0.f,0.f,0.f,0.f};

  #pragma unroll 1
  for(int ph = 0; ph < 2; ph++){
    const unsigned short* pa0 = (ph ? xin + (size_t)rA0*256 : aggX + (size_t)rA0*1536 + h*256) + w*8;
    const unsigned short* pa1 = (ph ? xin + (size_t)rA1*256 : aggX + (size_t)rA1*1536 + h*256) + w*8;
    const unsigned short* pbb = (ph ? rf : wf) + (size_t)h*121*256;
    const unsigned short* pb0 = pbb + (size_t)l*256 + w*8;
    const unsigned short* pb1 = pbb + (size_t)cB1*256 + w*8;
    #pragma unroll 1
    for(int kt = 0; kt < 256; kt += 64){
      #pragma unroll
      for(int jj = 0; jj < 2; jj++){
        int j = w + jj*4;             // slot
        int ko = kt + jj*32;
        __builtin_amdgcn_global_load_lds((const AS1 void*)(pa0 + ko), (AS3 void*)(a3A + j*1024),       16, 0, 0);
        __builtin_amdgcn_global_load_lds((const AS1 void*)(pa1 + ko), (AS3 void*)(a3A + j*1024 + 512), 16, 0, 0);
        __builtin_amdgcn_global_load_lds((const AS1 void*)(pb0 + ko), (AS3 void*)(a3B + j*1024),       16, 0, 0);
        __builtin_amdgcn_global_load_lds((const AS1 void*)(pb1 + ko), (AS3 void*)(a3B + j*1024 + 512), 16, 0, 0);
      }
      __syncthreads();
      #pragma unroll
      for(int ks = 0; ks < 2; ks++){
        bf16x8 af[4], bfr[4];
        #pragma unroll
        for(int f=0; f<4; f++){
          af[f]  = *(const bf16x8*)(sA + (ks*4 + (l>>4))*1024 + (wm*64 + f*16 + (l&15))*8);
          bfr[f] = *(const bf16x8*)(sB + (ks*4 + (l>>4))*1024 + (wn*64 + f*16 + (l&15))*8);
        }
        #pragma unroll
        for(int i=0;i<4;i++)
          #pragma unroll
          for(int j=0;j<4;j++)
            acc[i][j] = __builtin_amdgcn_mfma_f32_16x16x32_bf16(af[i], bfr[j], acc[i][j], 0, 0, 0);
      }
      __syncthreads();
    }
  }

  const float inv6 = 1.0f/6.0f;
  #pragma unroll
  for(int i=0;i<4;i++){
    int rbase = row0 + wm*64 + i*16 + (l>>4)*4;
    #pragma unroll
    for(int j=0;j<4;j++){
      int c = wn*64 + j*16 + (l&15);
      if(c < 121){
        #pragma unroll
        for(int q=0;q<4;q++){
          int r = rbase + q;
          if(r < M) atomicAdd(&outp[(size_t)r*121 + c], eluf(acc[i][j][q]) * inv6);
        }
      }
    }
  }
}

// ---------------- folded attention scalars (layer 0 only) ----------------
template<int H, int OS>
__global__ __launch_bounds__(256) void k_a12dot(const unsigned short* __restrict__ x,
    const float* __restrict__ fl, const float* __restrict__ fr,
    float* __restrict__ a1, float* __restrict__ a2){
  int n = blockIdx.x*4 + (threadIdx.x>>6);
  if(n >= NN) return;
  int l = threadIdx.x & 63;
  uint2 rv = *(const uint2*)(x + (size_t)n*256 + l*4);
  float c0 = lo16(rv.x), c1 = hi16(rv.x), c2 = lo16(rv.y), c3 = hi16(rv.y);
  float s1[H], s2[H];
  #pragma unroll
  for(int h = 0; h < H; h++){
    float4 vl = *(const float4*)(fl + h*256 + l*4);
    float4 vr = *(const float4*)(fr + h*256 + l*4);
    s1[h] = c0*vl.x + c1*vl.y + c2*vl.z + c3*vl.w;
    s2[h] = c0*vr.x + c1*vr.y + c2*vr.z + c3*vr.w;
  }
  #pragma unroll
  for(int off = 32; off > 0; off >>= 1){
    #pragma unroll
    for(int h = 0; h < H; h++){
      s1[h] += __shfl_xor(s1[h], off);
      s2[h] += __shfl_xor(s2[h], off);
    }
  }
  if(l == 0){
    #pragma unroll
    for(int h = 0; h < H; h++){ a1[(size_t)n*OS + h] = s1[h]; a2[(size_t)n*OS + h] = s2[h]; }
  }
}

// ---------------- aggregation H=4 K=64: CSR-ordered edge weights, unroll x4, fused next a12 ----------------
template<bool HAS_RES, int NH, int NOS>
__global__ __launch_bounds__(256) void k_agg4(const unsigned short* __restrict__ ft, int fts,
    const float* __restrict__ ex4,
    const int* __restrict__ row_ptr, const int* __restrict__ col_src,
    const unsigned short* __restrict__ res, int rs, unsigned short* __restrict__ outp,
    const float* __restrict__ nfl, const float* __restrict__ nfr,
    float* __restrict__ na1, float* __restrict__ na2){
  int n = blockIdx.x*4 + (threadIdx.x>>6);
  if(n >= NN) return;
  int l = threadIdx.x & 63;
  int h = l >> 4;
  int e0 = row_ptr[n], e1 = row_ptr[n+1];
  float acc0=0.f, acc1=0.f, acc2=0.f, acc3=0.f, d=0.f;
  int e = e0;
  for(; e + 4 <= e1; e += 4){
    int s0 = col_src[e], s1 = col_src[e+1], s2 = col_src[e+2], s3 = col_src[e+3];
    float x0 = ex4[(size_t)(e+0)*4 + h];
    float x1 = ex4[(size_t)(e+1)*4 + h];
    float x2 = ex4[(size_t)(e+2)*4 + h];
    float x3 = ex4[(size_t)(e+3)*4 + h];
    uint2 r0 = *(const uint2*)(ft + (size_t)s0*fts + l*4);
    uint2 r1 = *(const uint2*)(ft + (size_t)s1*fts + l*4);
    uint2 r2 = *(const uint2*)(ft + (size_t)s2*fts + l*4);
    uint2 r3 = *(const uint2*)(ft + (size_t)s3*fts + l*4);
    d += (x0 + x1) + (x2 + x3);
    acc0 += x0*lo16(r0.x) + x1*lo16(r1.x) + x2*lo16(r2.x) + x3*lo16(r3.x);
    acc1 += x0*hi16(r0.x) + x1*hi16(r1.x) + x2*hi16(r2.x) + x3*hi16(r3.x);
    acc2 += x0*lo16(r0.y) + x1*lo16(r1.y) + x2*lo16(r2.y) + x3*lo16(r3.y);
    acc3 += x0*hi16(r0.y) + x1*hi16(r1.y) + x2*hi16(r2.y) + x3*hi16(r3.y);
  }
  for(; e < e1; ++e){
    int s = col_src[e];
    float x = ex4[(size_t)e*4 + h];
    d += x;
    uint2 rv = *(const uint2*)(ft + (size_t)s*fts + l*4);
    acc0 += x*lo16(rv.x); acc1 += x*hi16(rv.x);
    acc2 += x*lo16(rv.y); acc3 += x*hi16(rv.y);
  }
  float inv = (e1 > e0) ? 1.0f/d : 0.0f;
  float v0 = acc0*inv, v1 = acc1*inv, v2 = acc2*inv, v3 = acc3*inv;
  if(HAS_RES){
    uint2 rr = *(const uint2*)(res + (size_t)n*rs + l*4);
    v0 += lo16(rr.x); v1 += hi16(rr.x); v2 += lo16(rr.y); v3 += hi16(rr.y);
  }
  float o0 = eluf(v0), o1 = eluf(v1), o2 = eluf(v2), o3 = eluf(v3);
  uint2 o;
  o.x = pack2(o0, o1);
  o.y = pack2(o2, o3);
  *(uint2*)(outp + (size_t)n*256 + l*4) = o;

  // fused a12 for next layer
  float s1[NH], s2[NH];
  #pragma unroll
  for(int hh = 0; hh < NH; hh++){
    float4 vl = *(const float4*)(nfl + hh*256 + l*4);
    float4 vr = *(const float4*)(nfr + hh*256 + l*4);
    s1[hh] = o0*vl.x + o1*vl.y + o2*vl.z + o3*vl.w;
    s2[hh] = o0*vr.x + o1*vr.y + o2*vr.z + o3*vr.w;
  }
  #pragma unroll
  for(int off = 32; off > 0; off >>= 1){
    #pragma unroll
    for(int hh = 0; hh < NH; hh++){
      s1[hh] += __shfl_xor(s1[hh], off);
      s2[hh] += __shfl_xor(s2[hh], off);
    }
  }
  if(l == 0){
    #pragma unroll
    for(int hh = 0; hh < NH; hh++){
      na1[(size_t)n*NOS + hh] = s1[hh];
      na2[(size_t)n*NOS + hh] = s2[hh];
    }
  }
}

// ---------------- final aggregation of x (6 heads), CSR-ordered weights, unroll x2 ----------------
__global__ __launch_bounds__(256) void k_aggx6(const unsigned short* __restrict__ x,
    const float* __restrict__ ex6,
    const int* __restrict__ row_ptr, const int* __restrict__ col_src,
    unsigned short* __restrict__ aggX){
  int n = blockIdx.x*4 + (threadIdx.x>>6);
  if(n >= NN) return;
  int l = threadIdx.x & 63;
  int e0 = row_ptr[n], e1 = row_ptr[n+1];
  float acc[6][4];
  float d[6];
  #pragma unroll
  for(int h=0;h<6;h++){ d[h]=0.f; acc[h][0]=0.f; acc[h][1]=0.f; acc[h][2]=0.f; acc[h][3]=0.f; }
  int e = e0;
  for(; e + 2 <= e1; e += 2){
    int s0 = col_src[e], s1 = col_src[e+1];
    float4 xl0 = *(const float4*)(ex6 + (size_t)(e+0)*8);
    float2 xh0 = *(const float2*)(ex6 + (size_t)(e+0)*8 + 4);
    float4 xl1 = *(const float4*)(ex6 + (size_t)(e+1)*8);
    float2 xh1 = *(const float2*)(ex6 + (size_t)(e+1)*8 + 4);
    uint2 rv0 = *(const uint2*)(x + (size_t)s0*256 + l*4);
    uint2 rv1 = *(const uint2*)(x + (size_t)s1*256 + l*4);
    float ex0[6] = {xl0.x, xl0.y, xl0.z, xl0.w, xh0.x, xh0.y};
    float ex1[6] = {xl1.x, xl1.y, xl1.z, xl1.w, xh1.x, xh1.y};
    float c00 = lo16(rv0.x), c01 = hi16(rv0.x), c02 = lo16(rv0.y), c03 = hi16(rv0.y);
    float c10 = lo16(rv1.x), c11 = hi16(rv1.x), c12 = lo16(rv1.y), c13 = hi16(rv1.y);
    #pragma unroll
    for(int h=0;h<6;h++){
      d[h] += ex0[h] + ex1[h];
      acc[h][0] += ex0[h]*c00 + ex1[h]*c10;
      acc[h][1] += ex0[h]*c01 + ex1[h]*c11;
      acc[h][2] += ex0[h]*c02 + ex1[h]*c12;
      acc[h][3] += ex0[h]*c03 + ex1[h]*c13;
    }
  }
  for(; e < e1; ++e){
    int s = col_src[e];
    float4 xl = *(const float4*)(ex6 + (size_t)e*8);
    float2 xh = *(const float2*)(ex6 + (size_t)e*8 + 4);
    uint2 rv = *(const uint2*)(x + (size_t)s*256 + l*4);
    float exv[6] = {xl.x, xl.y, xl.z, xl.w, xh.x, xh.y};
    float c0 = lo16(rv.x), c1 = hi16(rv.x), c2 = lo16(rv.y), c3 = hi16(rv.y);
    #pragma unroll
    for(int h=0;h<6;h++){
      d[h] += exv[h];
      acc[h][0] += exv[h]*c0;
      acc[h][1] += exv[h]*c1;
      acc[h][2] += exv[h]*c2;
      acc[h][3] += exv[h]*c3;
    }
  }
  bool deg = e1 > e0;
  #pragma unroll
  for(int h=0;h<6;h++){
    float inv = deg ? 1.0f/d[h] : 0.0f;
    uint2 o;
    o.x = pack2(acc[h][0]*inv, acc[h][1]*inv);
    o.y = pack2(acc[h][2]*inv, acc[h][3]*inv);
    *(uint2*)(aggX + (size_t)n*1536 + h*256 + l*4) = o;
  }
}

// ---------------- host ----------------
extern "C" void kernel_launch(void* const* d_in, const int* in_sizes, int n_in,
                              void* d_out, int out_size, void* d_ws, size_t ws_size,
                              hipStream_t stream){
  const float* features = (const float*)d_in[0];
  const int*   src      = (const int*)d_in[1];
  const int*   dst      = (const int*)d_in[2];
  const float* W0  = (const float*)d_in[3];
  const float* al0 = (const float*)d_in[4];
  const float* ar0 = (const float*)d_in[5];
  const float* W1  = (const float*)d_in[6];
  const float* al1 = (const float*)d_in[7];
  const float* ar1 = (const float*)d_in[8];
  const float* R1  = (const float*)d_in[9];
  const float* Wf  = (const float*)d_in[10];
  const float* alf = (const float*)d_in[11];
  const float* arf = (const float*)d_in[12];
  const float* Rf  = (const float*)d_in[13];
  float* out = (float*)d_out;
  (void)in_sizes; (void)n_in; (void)out_size;

  char* ws = (char*)d_ws;
  size_t off = 0;
  auto take = [&](size_t bytes) -> void* {
    void* p = ws + off;
    off += (bytes + 255) & ~(size_t)255;
    return p;
  };
  int* row_ptr = (int*)take((NN + 1) * sizeof(int));
  int* cur     = (int*)take(NN * sizeof(int));
  int* col_src = (int*)take(NE * sizeof(int));
  int* col_dst = (int*)take(NE * sizeof(int));
  int* bsum    = (int*)take(256 * sizeof(int));
  int* boff    = (int*)take(257 * sizeof(int));
  float* a1A = (float*)take((size_t)NN * 8 * sizeof(float));
  float* a2A = (float*)take((size_t)NN * 8 * sizeof(float));
  float* a1B = (float*)take((size_t)NN * 8 * sizeof(float));
  float* a2B = (float*)take((size_t)NN * 8 * sizeof(float));
  // hB16 first (alive in final phase); then ftres/feat16/hA16 (dead in final phase)
  // + fresh 51.2MB tail -> contiguous 153.6MB region for aggX aliasing.
  unsigned short* hB16   = (unsigned short*)take((size_t)NN * 256 * 2);  // 25.6 MB
  unsigned short* ftres  = (unsigned short*)take((size_t)NN * 512 * 2);  // 51.2 MB
  unsigned short* feat16 = (unsigned short*)take((size_t)NN * 256 * 2);  // 25.6 MB
  unsigned short* hA16   = (unsigned short*)take((size_t)NN * 256 * 2);  // 25.6 MB
  unsigned short* aggtl  = (unsigned short*)take((size_t)NN * 512 * 2);  // 51.2 MB fresh tail
  float* ex4 = (float*)take((size_t)NE * 4 * sizeof(float));             // 6.4 MB
  float* ex6 = (float*)take((size_t)NE * 8 * sizeof(float));             // 12.8 MB
  unsigned short* w016  = (unsigned short*)take(65536 * 2);
  unsigned short* w1r1  = (unsigned short*)take(131072 * 2);
  unsigned short* wf16  = (unsigned short*)take(185856 * 2);
  unsigned short* rf16  = (unsigned short*)take(185856 * 2);
  float* fl0 = (float*)take(4*256*sizeof(float));
  float* fr0 = (float*)take(4*256*sizeof(float));
  float* fl1 = (float*)take(4*256*sizeof(float));
  float* fr1 = (float*)take(4*256*sizeof(float));
  float* flF = (float*)take(6*256*sizeof(float));
  float* frF = (float*)take(6*256*sizeof(float));
  size_t need = off;
  (void)aggtl;

  if(ws_size < need){
    k_diag<<<1, 1, 0, stream>>>(out, 100.0f + (float)((double)ws_size / 1073741824.0));
    return;
  }

  // aggX [NN][6][256] bf16 (153.6MB) aliases ftres+feat16+hA16+aggtl (all dead in final phase)
  unsigned short* aggX = ftres;

  // CSR build
  hipMemsetAsync(cur, 0, NN * sizeof(int), stream);
  k_count<<<(NE + 255)/256, 256, 0, stream>>>(dst, cur, NE);
  k_scanA<<<NB, 256, 0, stream>>>(cur, row_ptr, bsum, NN);
  k_scanB<<<1, 256, 0, stream>>>(bsum, boff, NB);
  k_scanC<<<NB, 256, 0, stream>>>(row_ptr, boff, NN, NB);
  hipMemsetAsync(cur, 0, NN * sizeof(int), stream);
  k_scatter<<<(NE + 255)/256, 256, 0, stream>>>(src, dst, row_ptr, cur, col_src, col_dst, NE);

  // converts + folds
  k_cvt<<<(NN*256/4 + 255)/256, 256, 0, stream>>>(features, feat16, NN*256);
  k_cvt3<<<dim3(64, 3), 256, 0, stream>>>(W0, W1, R1, w016, w1r1, w1r1 + 65536, 65536);
  k_cvt2<<<dim3(182, 2), 256, 0, stream>>>(Wf, Rf, wf16, rf16, 185856);
  k_foldAll<<<14, 256, 0, stream>>>(W0, al0, ar0, W1, al1, ar1, Wf, alf, arf,
                                    fl0, fr0, fl1, fr1, flF, frF);

  int gm = (NN + 127) / 128;     // 391
  int gagg = (NN + 3) / 4;       // 12500
  int gedge = (NE + 255) / 256;  // 1563

  // Layer 0: a12(A) -> edge-exp (CSR order) -> GEMM -> agg (writes hA + next a12 into B)
  k_a12dot<4,4><<<gagg, 256, 0, stream>>>(feat16, fl0, fr0, a1A, a2A);
  k_eexp<4><<<gedge, 256, 0, stream>>>(col_src, col_dst, a1A, a2A, ex4);
  k_gemm16<<<dim3(gm, 2), 256, 0, stream>>>(feat16, w016, ftres, NN, 256, 256);
  k_agg4<false,4,4><<<gagg, 256, 0, stream>>>(ftres, 256, ex4, row_ptr, col_src,
      nullptr, 0, hA16, fl1, fr1, a1B, a2B);

  // Layer 1: edge-exp -> fused [W1;R1] GEMM (stride-512) -> agg (writes hB + final a12 into A)
  k_eexp<4><<<gedge, 256, 0, stream>>>(col_src, col_dst, a1B, a2B, ex4);
  k_gemm16<<<dim3(gm, 4), 256, 0, stream>>>(hA16, w1r1, ftres, NN, 512, 512);
  k_agg4<true,6,8><<<gagg, 256, 0, stream>>>(ftres, 512, ex4, row_ptr, col_src,
      ftres + 256, 512, hB16, flF, frF, a1A, a2A);

  // Final layer: edge-exp -> aggregate x -> head-parallel GEMM (BK=64) with fp32 atomic mean
  k_eexp<8><<<gedge, 256, 0, stream>>>(col_src, col_dst, a1A, a2A, ex6);
  k_aggx6<<<gagg, 256, 0, stream>>>(hB16, ex6, row_ptr, col_src, aggX);
  hipMemsetAsync(out, 0, (size_t)NN * 121 * sizeof(float), stream);
  k_gemmFh<<<dim3(gm, 6), 256, 0, stream>>>(aggX, hB16, wf16, rf16, out, NN);
}

// Round 11
// 514.616 us; speedup vs baseline: 1.2367x; 1.2367x over previous
//
#include <hip/hip_runtime.h>
#include <math.h>

#define NN 50000
#define NE 400000
#define NB ((NN + 255) / 256)   // 196 scan blocks

typedef __attribute__((ext_vector_type(8))) short bf16x8;
typedef __attribute__((ext_vector_type(4))) float f32x4;
#define AS1 __attribute__((address_space(1)))
#define AS3 __attribute__((address_space(3)))

__device__ __forceinline__ float lrelu(float x){ return x > 0.0f ? x : 0.01f*x; }
__device__ __forceinline__ float eluf(float x){ return x > 0.0f ? x : __expf(x)-1.0f; }
__device__ __forceinline__ float bf2f(unsigned short u){
  union{unsigned i; float f;} v; v.i = ((unsigned)u)<<16; return v.f;
}
__device__ __forceinline__ unsigned short f2bf(float x){
  union{float f; unsigned i;} v; v.f = x;
  unsigned r = v.i + 0x7FFFu + ((v.i>>16)&1u);
  return (unsigned short)(r>>16);
}
__device__ __forceinline__ unsigned pack2(float a, float b){
  return (unsigned)f2bf(a) | ((unsigned)f2bf(b)<<16);
}
__device__ __forceinline__ float lo16(unsigned u){ return bf2f((unsigned short)(u & 0xffffu)); }
__device__ __forceinline__ float hi16(unsigned u){ return bf2f((unsigned short)(u >> 16)); }

// ---------------- diagnostic ----------------
__global__ void k_diag(float* out, float val){ out[0] = val; }

// ---------------- fp32 -> bf16 convert ----------------
__global__ void k_cvt(const float* __restrict__ in, unsigned short* __restrict__ o, int n){
  int i = (blockIdx.x*256 + threadIdx.x)*4;
  if(i + 3 < n){
    float4 v = *(const float4*)(in + i);
    uint2 p; p.x = pack2(v.x, v.y); p.y = pack2(v.z, v.w);
    *(uint2*)(o + i) = p;
  } else {
    for(int k = i; k < n; k++) o[k] = f2bf(in[k]);
  }
}

__global__ void k_cvt3(const float* __restrict__ s0, const float* __restrict__ s1,
    const float* __restrict__ s2, unsigned short* __restrict__ d0,
    unsigned short* __restrict__ d1, unsigned short* __restrict__ d2, int n){
  const float* in = (blockIdx.y == 0) ? s0 : (blockIdx.y == 1) ? s1 : s2;
  unsigned short* o = (blockIdx.y == 0) ? d0 : (blockIdx.y == 1) ? d1 : d2;
  int i = (blockIdx.x*256 + threadIdx.x)*4;
  if(i + 3 < n){
    float4 v = *(const float4*)(in + i);
    uint2 p; p.x = pack2(v.x, v.y); p.y = pack2(v.z, v.w);
    *(uint2*)(o + i) = p;
  } else {
    for(int k = i; k < n; k++) o[k] = f2bf(in[k]);
  }
}

__global__ void k_cvt2(const float* __restrict__ s0, const float* __restrict__ s1,
    unsigned short* __restrict__ d0, unsigned short* __restrict__ d1, int n){
  const float* in = (blockIdx.y == 0) ? s0 : s1;
  unsigned short* o = (blockIdx.y == 0) ? d0 : d1;
  int i = (blockIdx.x*256 + threadIdx.x)*4;
  if(i + 3 < n){
    float4 v = *(const float4*)(in + i);
    uint2 p; p.x = pack2(v.x, v.y); p.y = pack2(v.z, v.w);
    *(uint2*)(o + i) = p;
  } else {
    for(int k = i; k < n; k++) o[k] = f2bf(in[k]);
  }
}

// ---------------- all folds in one launch ----------------
__global__ void k_foldAll(const float* __restrict__ W0, const float* __restrict__ al0, const float* __restrict__ ar0,
    const float* __restrict__ W1, const float* __restrict__ al1, const float* __restrict__ ar1,
    const float* __restrict__ Wf, const float* __restrict__ alf, const float* __restrict__ arf,
    float* __restrict__ fl0, float* __restrict__ fr0, float* __restrict__ fl1, float* __restrict__ fr1,
    float* __restrict__ flF, float* __restrict__ frF){
  int b = blockIdx.x, d = threadIdx.x;
  const float *W, *al, *ar; float *fl, *fr; int K, h;
  if(b < 4){ W=W0; al=al0; ar=ar0; fl=fl0; fr=fr0; K=64; h=b; }
  else if(b < 8){ W=W1; al=al1; ar=ar1; fl=fl1; fr=fr1; K=64; h=b-4; }
  else { W=Wf; al=alf; ar=arf; fl=flF; fr=frF; K=121; h=b-8; }
  float sl = 0.f, sr = 0.f;
  const float* wb = W + ((size_t)h*K)*256 + d;
  for(int k = 0; k < K; k++){
    float w = wb[(size_t)k*256];
    sl += al[h*K + k]*w;
    sr += ar[h*K + k]*w;
  }
  fl[h*256 + d] = sl;
  fr[h*256 + d] = sr;
}

// ---------------- CSR build ----------------
__global__ void k_count(const int* __restrict__ dst, int* __restrict__ cnt, int E){
  int e = blockIdx.x * 256 + threadIdx.x;
  if(e < E) atomicAdd(&cnt[dst[e]], 1);
}

__global__ void k_scanA(const int* __restrict__ cnt, int* __restrict__ row_ptr,
    int* __restrict__ bsum, int N){
  __shared__ int sh[256];
  int t = threadIdx.x;
  int i = blockIdx.x*256 + t;
  int v = (i < N) ? cnt[i] : 0;
  sh[t] = v;
  __syncthreads();
  for(int off = 1; off < 256; off <<= 1){
    int u = (t >= off) ? sh[t - off] : 0;
    __syncthreads();
    sh[t] += u;
    __syncthreads();
  }
  if(i < N) row_ptr[i] = sh[t] - v;
  if(t == 255) bsum[blockIdx.x] = sh[255];
}

__global__ void k_scanB(const int* __restrict__ bsum, int* __restrict__ boff, int nb){
  __shared__ int sh[256];
  int t = threadIdx.x;
  int v = (t < nb) ? bsum[t] : 0;
  sh[t] = v;
  __syncthreads();
  for(int off = 1; off < 256; off <<= 1){
    int u = (t >= off) ? sh[t - off] : 0;
    __syncthreads();
    sh[t] += u;
    __syncthreads();
  }
  if(t < nb) boff[t] = sh[t] - v;
  if(t == 255) boff[nb] = sh[255];
}

__global__ void k_scanC(int* __restrict__ row_ptr, const int* __restrict__ boff, int N, int nb){
  int i = blockIdx.x*256 + threadIdx.x;
  if(i < N) row_ptr[i] += boff[blockIdx.x];
  if(i == 0) row_ptr[N] = boff[nb];
}

// scatter: also record the dst node per CSR position
__global__ void k_scatter(const int* __restrict__ src, const int* __restrict__ dst,
    const int* __restrict__ row_ptr, int* __restrict__ cur,
    int* __restrict__ col_src, int* __restrict__ col_dst, int E){
  int e = blockIdx.x * 256 + threadIdx.x;
  if(e < E){
    int d = dst[e];
    int pos = row_ptr[d] + atomicAdd(&cur[d], 1);
    col_src[pos] = src[e];
    col_dst[pos] = d;
  }
}

// ---------------- edge-exp precompute (CSR order) ----------------
template<int S>
__global__ __launch_bounds__(256) void k_eexp(const int* __restrict__ col_src, const int* __restrict__ col_dst,
    const float* __restrict__ a1, const float* __restrict__ a2, float* __restrict__ ex){
  int p = blockIdx.x*256 + threadIdx.x;
  if(p >= NE) return;
  int s = col_src[p], d = col_dst[p];
  if(S == 4){
    float4 v1 = *(const float4*)(a1 + (size_t)d*4);
    float4 v2 = *(const float4*)(a2 + (size_t)s*4);
    float4 o;
    o.x = __expf(lrelu(v1.x + v2.x));
    o.y = __expf(lrelu(v1.y + v2.y));
    o.z = __expf(lrelu(v1.z + v2.z));
    o.w = __expf(lrelu(v1.w + v2.w));
    *(float4*)(ex + (size_t)p*4) = o;
  } else {
    float4 l1 = *(const float4*)(a1 + (size_t)d*8);
    float2 h1 = *(const float2*)(a1 + (size_t)d*8 + 4);
    float4 l2 = *(const float4*)(a2 + (size_t)s*8);
    float2 h2 = *(const float2*)(a2 + (size_t)s*8 + 4);
    float4 o;
    o.x = __expf(lrelu(l1.x + l2.x));
    o.y = __expf(lrelu(l1.y + l2.y));
    o.z = __expf(lrelu(l1.z + l2.z));
    o.w = __expf(lrelu(l1.w + l2.w));
    float2 o2;
    o2.x = __expf(lrelu(h1.x + h2.x));
    o2.y = __expf(lrelu(h1.y + h2.y));
    *(float4*)(ex + (size_t)p*8) = o;
    *(float2*)(ex + (size_t)p*8 + 4) = o2;
  }
}

// ---------------- bf16 MFMA GEMM (128x128 tile, BK=32, 4 waves of 64x64) ----------------
__global__ __launch_bounds__(256) void k_gemm16(const unsigned short* __restrict__ X,
    const unsigned short* __restrict__ W, unsigned short* __restrict__ out,
    int N, int Kout, int ostride){
  __shared__ unsigned short sA[4096];
  __shared__ unsigned short sB[4096];
  int tid = threadIdx.x;
  int l = tid & 63, w = tid >> 6;
  int wm = w >> 1, wn = w & 1;
  int row0 = blockIdx.x*128, col0 = blockIdx.y*128;

  f32x4 acc[4][4];
  #pragma unroll
  for(int i=0;i<4;i++)
    #pragma unroll
    for(int j=0;j<4;j++) acc[i][j] = (f32x4){0.f,0.f,0.f,0.f};

  int grA0 = row0 + l;        if(grA0 >= N) grA0 = 0;
  int grA1 = row0 + 64 + l;   if(grA1 >= N) grA1 = 0;
  int gcB0 = col0 + l;        if(gcB0 >= Kout) gcB0 = 0;
  int gcB1 = col0 + 64 + l;   if(gcB1 >= Kout) gcB1 = 0;
  const unsigned short* pa0 = X + (size_t)grA0*256 + w*8;
  const unsigned short* pa1 = X + (size_t)grA1*256 + w*8;
  const unsigned short* pb0 = W + (size_t)gcB0*256 + w*8;
  const unsigned short* pb1 = W + (size_t)gcB1*256 + w*8;

  AS3 unsigned short* a3A = (AS3 unsigned short*)sA;
  AS3 unsigned short* a3B = (AS3 unsigned short*)sB;

  for(int kt = 0; kt < 256; kt += 32){
    __builtin_amdgcn_global_load_lds((const AS1 void*)(pa0 + kt), (AS3 void*)(a3A + w*1024),       16, 0, 0);
    __builtin_amdgcn_global_load_lds((const AS1 void*)(pa1 + kt), (AS3 void*)(a3A + w*1024 + 512), 16, 0, 0);
    __builtin_amdgcn_global_load_lds((const AS1 void*)(pb0 + kt), (AS3 void*)(a3B + w*1024),       16, 0, 0);
    __builtin_amdgcn_global_load_lds((const AS1 void*)(pb1 + kt), (AS3 void*)(a3B + w*1024 + 512), 16, 0, 0);
    __syncthreads();
    bf16x8 af[4], bfr[4];
    #pragma unroll
    for(int f=0; f<4; f++){
      af[f]  = *(const bf16x8*)(sA + (l>>4)*1024 + (wm*64 + f*16 + (l&15))*8);
      bfr[f] = *(const bf16x8*)(sB + (l>>4)*1024 + (wn*64 + f*16 + (l&15))*8);
    }
    #pragma unroll
    for(int i=0;i<4;i++)
      #pragma unroll
      for(int j=0;j<4;j++)
        acc[i][j] = __builtin_amdgcn_mfma_f32_16x16x32_bf16(af[i], bfr[j], acc[i][j], 0, 0, 0);
    __syncthreads();
  }

  #pragma unroll
  for(int i=0;i<4;i++){
    int rbase = row0 + wm*64 + i*16 + (l>>4)*4;
    #pragma unroll
    for(int j=0;j<4;j++){
      int c = col0 + wn*64 + j*16 + (l&15);
      if(c < Kout){
        #pragma unroll
        for(int q=0;q<4;q++){
          int r = rbase + q;
          if(r < N) out[(size_t)r*ostride + c] = f2bf(acc[i][j][q]);
        }
      }
    }
  }
}

// ---------------- final GEMM, one head per block, BK=64; bf16 elu partials ----------------
__global__ __launch_bounds__(256) void k_gemmFh(const unsigned short* __restrict__ aggX,
    const unsigned short* __restrict__ xin, const unsigned short* __restrict__ wf,
    const unsigned short* __restrict__ rf, unsigned short* __restrict__ partial, int M){
  __shared__ unsigned short sA[8192];   // [slot 8][row 128][8]
  __shared__ unsigned short sB[8192];
  int tid = threadIdx.x;
  int l = tid & 63, w = tid >> 6;
  int wm = w >> 1, wn = w & 1;
  int h = blockIdx.y;
  int row0 = blockIdx.x*128;
  int rA0 = row0 + l;      if(rA0 >= M) rA0 = 0;
  int rA1 = row0 + 64 + l; if(rA1 >= M) rA1 = 0;
  int cB1 = 64 + l; if(cB1 > 120) cB1 = 120;

  AS3 unsigned short* a3A = (AS3 unsigned short*)sA;
  AS3 unsigned short* a3B = (AS3 unsigned short*)sB;

  f32x4 acc[4][4];
  #pragma unroll
  for(int i=0;i<4;i++)
    #pragma unroll
    for(int j=0;j<4;j++) acc[i][j] = (f32x4){0.f,0.f,0.f,0.f};

  #pragma unroll 1
  for(int ph = 0; ph < 2; ph++){
    const unsigned short* pa0 = (ph ? xin + (size_t)rA0*256 : aggX + (size_t)rA0*1536 + h*256) + w*8;
    const unsigned short* pa1 = (ph ? xin + (size_t)rA1*256 : aggX + (size_t)rA1*1536 + h*256) + w*8;
    const unsigned short* pbb = (ph ? rf : wf) + (size_t)h*121*256;
    const unsigned short* pb0 = pbb + (size_t)l*256 + w*8;
    const unsigned short* pb1 = pbb + (size_t)cB1*256 + w*8;
    #pragma unroll 1
    for(int kt = 0; kt < 256; kt += 64){
      #pragma unroll
      for(int jj = 0; jj < 2; jj++){
        int j = w + jj*4;             // slot
        int ko = kt + jj*32;
        __builtin_amdgcn_global_load_lds((const AS1 void*)(pa0 + ko), (AS3 void*)(a3A + j*1024),       16, 0, 0);
        __builtin_amdgcn_global_load_lds((const AS1 void*)(pa1 + ko), (AS3 void*)(a3A + j*1024 + 512), 16, 0, 0);
        __builtin_amdgcn_global_load_lds((const AS1 void*)(pb0 + ko), (AS3 void*)(a3B + j*1024),       16, 0, 0);
        __builtin_amdgcn_global_load_lds((const AS1 void*)(pb1 + ko), (AS3 void*)(a3B + j*1024 + 512), 16, 0, 0);
      }
      __syncthreads();
      #pragma unroll
      for(int ks = 0; ks < 2; ks++){
        bf16x8 af[4], bfr[4];
        #pragma unroll
        for(int f=0; f<4; f++){
          af[f]  = *(const bf16x8*)(sA + (ks*4 + (l>>4))*1024 + (wm*64 + f*16 + (l&15))*8);
          bfr[f] = *(const bf16x8*)(sB + (ks*4 + (l>>4))*1024 + (wn*64 + f*16 + (l&15))*8);
        }
        #pragma unroll
        for(int i=0;i<4;i++)
          #pragma unroll
          for(int j=0;j<4;j++)
            acc[i][j] = __builtin_amdgcn_mfma_f32_16x16x32_bf16(af[i], bfr[j], acc[i][j], 0, 0, 0);
      }
      __syncthreads();
    }
  }

  unsigned short* pb = partial + (size_t)h*M*128;
  #pragma unroll
  for(int i=0;i<4;i++){
    int rbase = row0 + wm*64 + i*16 + (l>>4)*4;
    #pragma unroll
    for(int j=0;j<4;j++){
      int c = wn*64 + j*16 + (l&15);
      #pragma unroll
      for(int q=0;q<4;q++){
        int r = rbase + q;
        if(r < M) pb[(size_t)r*128 + c] = f2bf(eluf(acc[i][j][q]));
      }
    }
  }
}

// ---------------- reduce 6 bf16 head partials -> out ----------------
__global__ __launch_bounds__(256) void k_reduce6(const unsigned short* __restrict__ partial,
    float* __restrict__ outp, int n0, int M){
  int t = blockIdx.x*256 + threadIdx.x;
  int idx = t >> 7, c = t & 127;
  if(idx >= M || c >= 121) return;
  float s = 0.f;
  #pragma unroll
  for(int h = 0; h < 6; h++) s += bf2f(partial[((size_t)h*M + idx)*128 + c]);
  outp[(size_t)(n0 + idx)*121 + c] = s * (1.0f/6.0f);
}

// ---------------- folded attention scalars (layer 0 only) ----------------
template<int H, int OS>
__global__ __launch_bounds__(256) void k_a12dot(const unsigned short* __restrict__ x,
    const float* __restrict__ fl, const float* __restrict__ fr,
    float* __restrict__ a1, float* __restrict__ a2){
  int n = blockIdx.x*4 + (threadIdx.x>>6);
  if(n >= NN) return;
  int l = threadIdx.x & 63;
  uint2 rv = *(const uint2*)(x + (size_t)n*256 + l*4);
  float c0 = lo16(rv.x), c1 = hi16(rv.x), c2 = lo16(rv.y), c3 = hi16(rv.y);
  float s1[H], s2[H];
  #pragma unroll
  for(int h = 0; h < H; h++){
    float4 vl = *(const float4*)(fl + h*256 + l*4);
    float4 vr = *(const float4*)(fr + h*256 + l*4);
    s1[h] = c0*vl.x + c1*vl.y + c2*vl.z + c3*vl.w;
    s2[h] = c0*vr.x + c1*vr.y + c2*vr.z + c3*vr.w;
  }
  #pragma unroll
  for(int off = 32; off > 0; off >>= 1){
    #pragma unroll
    for(int h = 0; h < H; h++){
      s1[h] += __shfl_xor(s1[h], off);
      s2[h] += __shfl_xor(s2[h], off);
    }
  }
  if(l == 0){
    #pragma unroll
    for(int h = 0; h < H; h++){ a1[(size_t)n*OS + h] = s1[h]; a2[(size_t)n*OS + h] = s2[h]; }
  }
}

// ---------------- aggregation H=4 K=64: CSR-ordered edge weights, unroll x4, fused next a12 ----------------
template<bool HAS_RES, int NH, int NOS>
__global__ __launch_bounds__(256) void k_agg4(const unsigned short* __restrict__ ft, int fts,
    const float* __restrict__ ex4,
    const int* __restrict__ row_ptr, const int* __restrict__ col_src,
    const unsigned short* __restrict__ res, int rs, unsigned short* __restrict__ outp,
    const float* __restrict__ nfl, const float* __restrict__ nfr,
    float* __restrict__ na1, float* __restrict__ na2){
  int n = blockIdx.x*4 + (threadIdx.x>>6);
  if(n >= NN) return;
  int l = threadIdx.x & 63;
  int h = l >> 4;
  int e0 = row_ptr[n], e1 = row_ptr[n+1];
  float acc0=0.f, acc1=0.f, acc2=0.f, acc3=0.f, d=0.f;
  int e = e0;
  for(; e + 4 <= e1; e += 4){
    int s0 = col_src[e], s1 = col_src[e+1], s2 = col_src[e+2], s3 = col_src[e+3];
    float x0 = ex4[(size_t)(e+0)*4 + h];
    float x1 = ex4[(size_t)(e+1)*4 + h];
    float x2 = ex4[(size_t)(e+2)*4 + h];
    float x3 = ex4[(size_t)(e+3)*4 + h];
    uint2 r0 = *(const uint2*)(ft + (size_t)s0*fts + l*4);
    uint2 r1 = *(const uint2*)(ft + (size_t)s1*fts + l*4);
    uint2 r2 = *(const uint2*)(ft + (size_t)s2*fts + l*4);
    uint2 r3 = *(const uint2*)(ft + (size_t)s3*fts + l*4);
    d += (x0 + x1) + (x2 + x3);
    acc0 += x0*lo16(r0.x) + x1*lo16(r1.x) + x2*lo16(r2.x) + x3*lo16(r3.x);
    acc1 += x0*hi16(r0.x) + x1*hi16(r1.x) + x2*hi16(r2.x) + x3*hi16(r3.x);
    acc2 += x0*lo16(r0.y) + x1*lo16(r1.y) + x2*lo16(r2.y) + x3*lo16(r3.y);
    acc3 += x0*hi16(r0.y) + x1*hi16(r1.y) + x2*hi16(r2.y) + x3*hi16(r3.y);
  }
  for(; e < e1; ++e){
    int s = col_src[e];
    float x = ex4[(size_t)e*4 + h];
    d += x;
    uint2 rv = *(const uint2*)(ft + (size_t)s*fts + l*4);
    acc0 += x*lo16(rv.x); acc1 += x*hi16(rv.x);
    acc2 += x*lo16(rv.y); acc3 += x*hi16(rv.y);
  }
  float inv = (e1 > e0) ? 1.0f/d : 0.0f;
  float v0 = acc0*inv, v1 = acc1*inv, v2 = acc2*inv, v3 = acc3*inv;
  if(HAS_RES){
    uint2 rr = *(const uint2*)(res + (size_t)n*rs + l*4);
    v0 += lo16(rr.x); v1 += hi16(rr.x); v2 += lo16(rr.y); v3 += hi16(rr.y);
  }
  float o0 = eluf(v0), o1 = eluf(v1), o2 = eluf(v2), o3 = eluf(v3);
  uint2 o;
  o.x = pack2(o0, o1);
  o.y = pack2(o2, o3);
  *(uint2*)(outp + (size_t)n*256 + l*4) = o;

  // fused a12 for next layer
  float s1[NH], s2[NH];
  #pragma unroll
  for(int hh = 0; hh < NH; hh++){
    float4 vl = *(const float4*)(nfl + hh*256 + l*4);
    float4 vr = *(const float4*)(nfr + hh*256 + l*4);
    s1[hh] = o0*vl.x + o1*vl.y + o2*vl.z + o3*vl.w;
    s2[hh] = o0*vr.x + o1*vr.y + o2*vr.z + o3*vr.w;
  }
  #pragma unroll
  for(int off = 32; off > 0; off >>= 1){
    #pragma unroll
    for(int hh = 0; hh < NH; hh++){
      s1[hh] += __shfl_xor(s1[hh], off);
      s2[hh] += __shfl_xor(s2[hh], off);
    }
  }
  if(l == 0){
    #pragma unroll
    for(int hh = 0; hh < NH; hh++){
      na1[(size_t)n*NOS + hh] = s1[hh];
      na2[(size_t)n*NOS + hh] = s2[hh];
    }
  }
}

// ---------------- final aggregation of x (6 heads), CSR-ordered weights, unroll x2 ----------------
__global__ __launch_bounds__(256) void k_aggx6(const unsigned short* __restrict__ x,
    const float* __restrict__ ex6,
    const int* __restrict__ row_ptr, const int* __restrict__ col_src,
    unsigned short* __restrict__ aggX, int n0base, int M){
  int idx = blockIdx.x*4 + (threadIdx.x>>6);
  if(idx >= M) return;
  int n = n0base + idx;
  int l = threadIdx.x & 63;
  int e0 = row_ptr[n], e1 = row_ptr[n+1];
  float acc[6][4];
  float d[6];
  #pragma unroll
  for(int h=0;h<6;h++){ d[h]=0.f; acc[h][0]=0.f; acc[h][1]=0.f; acc[h][2]=0.f; acc[h][3]=0.f; }
  int e = e0;
  for(; e + 2 <= e1; e += 2){
    int s0 = col_src[e], s1 = col_src[e+1];
    float4 xl0 = *(const float4*)(ex6 + (size_t)(e+0)*8);
    float2 xh0 = *(const float2*)(ex6 + (size_t)(e+0)*8 + 4);
    float4 xl1 = *(const float4*)(ex6 + (size_t)(e+1)*8);
    float2 xh1 = *(const float2*)(ex6 + (size_t)(e+1)*8 + 4);
    uint2 rv0 = *(const uint2*)(x + (size_t)s0*256 + l*4);
    uint2 rv1 = *(const uint2*)(x + (size_t)s1*256 + l*4);
    float ex0[6] = {xl0.x, xl0.y, xl0.z, xl0.w, xh0.x, xh0.y};
    float ex1[6] = {xl1.x, xl1.y, xl1.z, xl1.w, xh1.x, xh1.y};
    float c00 = lo16(rv0.x), c01 = hi16(rv0.x), c02 = lo16(rv0.y), c03 = hi16(rv0.y);
    float c10 = lo16(rv1.x), c11 = hi16(rv1.x), c12 = lo16(rv1.y), c13 = hi16(rv1.y);
    #pragma unroll
    for(int h=0;h<6;h++){
      d[h] += ex0[h] + ex1[h];
      acc[h][0] += ex0[h]*c00 + ex1[h]*c10;
      acc[h][1] += ex0[h]*c01 + ex1[h]*c11;
      acc[h][2] += ex0[h]*c02 + ex1[h]*c12;
      acc[h][3] += ex0[h]*c03 + ex1[h]*c13;
    }
  }
  for(; e < e1; ++e){
    int s = col_src[e];
    float4 xl = *(const float4*)(ex6 + (size_t)e*8);
    float2 xh = *(const float2*)(ex6 + (size_t)e*8 + 4);
    uint2 rv = *(const uint2*)(x + (size_t)s*256 + l*4);
    float exv[6] = {xl.x, xl.y, xl.z, xl.w, xh.x, xh.y};
    float c0 = lo16(rv.x), c1 = hi16(rv.x), c2 = lo16(rv.y), c3 = hi16(rv.y);
    #pragma unroll
    for(int h=0;h<6;h++){
      d[h] += exv[h];
      acc[h][0] += exv[h]*c0;
      acc[h][1] += exv[h]*c1;
      acc[h][2] += exv[h]*c2;
      acc[h][3] += exv[h]*c3;
    }
  }
  bool deg = e1 > e0;
  #pragma unroll
  for(int h=0;h<6;h++){
    float inv = deg ? 1.0f/d[h] : 0.0f;
    uint2 o;
    o.x = pack2(acc[h][0]*inv, acc[h][1]*inv);
    o.y = pack2(acc[h][2]*inv, acc[h][3]*inv);
    *(uint2*)(aggX + (size_t)idx*1536 + h*256 + l*4) = o;
  }
}

// ---------------- host ----------------
extern "C" void kernel_launch(void* const* d_in, const int* in_sizes, int n_in,
                              void* d_out, int out_size, void* d_ws, size_t ws_size,
                              hipStream_t stream){
  const float* features = (const float*)d_in[0];
  const int*   src      = (const int*)d_in[1];
  const int*   dst      = (const int*)d_in[2];
  const float* W0  = (const float*)d_in[3];
  const float* al0 = (const float*)d_in[4];
  const float* ar0 = (const float*)d_in[5];
  const float* W1  = (const float*)d_in[6];
  const float* al1 = (const float*)d_in[7];
  const float* ar1 = (const float*)d_in[8];
  const float* R1  = (const float*)d_in[9];
  const float* Wf  = (const float*)d_in[10];
  const float* alf = (const float*)d_in[11];
  const float* arf = (const float*)d_in[12];
  const float* Rf  = (const float*)d_in[13];
  float* out = (float*)d_out;
  (void)in_sizes; (void)n_in; (void)out_size;

  char* ws = (char*)d_ws;
  size_t off = 0;
  auto take = [&](size_t bytes) -> void* {
    void* p = ws + off;
    off += (bytes + 255) & ~(size_t)255;
    return p;
  };
  const int CH = 25000;
  int* row_ptr = (int*)take((NN + 1) * sizeof(int));
  int* cur     = (int*)take(NN * sizeof(int));
  int* col_src = (int*)take(NE * sizeof(int));
  int* col_dst = (int*)take(NE * sizeof(int));
  int* bsum    = (int*)take(256 * sizeof(int));
  int* boff    = (int*)take(257 * sizeof(int));
  float* a1A = (float*)take((size_t)NN * 8 * sizeof(float));
  float* a2A = (float*)take((size_t)NN * 8 * sizeof(float));
  float* a1B = (float*)take((size_t)NN * 8 * sizeof(float));
  float* a2B = (float*)take((size_t)NN * 8 * sizeof(float));
  // hB16 first (alive in final phase); ftres+feat16 contiguous (76.8MB) -> aggX alias;
  // hA16+aggtl contiguous -> partial alias (38.4MB).
  unsigned short* hB16   = (unsigned short*)take((size_t)NN * 256 * 2);  // 25.6 MB
  unsigned short* ftres  = (unsigned short*)take((size_t)NN * 512 * 2);  // 51.2 MB
  unsigned short* feat16 = (unsigned short*)take((size_t)NN * 256 * 2);  // 25.6 MB
  unsigned short* hA16   = (unsigned short*)take((size_t)NN * 256 * 2);  // 25.6 MB
  unsigned short* aggtl  = (unsigned short*)take((size_t)NN * 512 * 2);  // 51.2 MB
  float* ex4 = (float*)take((size_t)NE * 4 * sizeof(float));             // 6.4 MB
  float* ex6 = (float*)take((size_t)NE * 8 * sizeof(float));             // 12.8 MB
  unsigned short* w016  = (unsigned short*)take(65536 * 2);
  unsigned short* w1r1  = (unsigned short*)take(131072 * 2);
  unsigned short* wf16  = (unsigned short*)take(185856 * 2);
  unsigned short* rf16  = (unsigned short*)take(185856 * 2);
  float* fl0 = (float*)take(4*256*sizeof(float));
  float* fr0 = (float*)take(4*256*sizeof(float));
  float* fl1 = (float*)take(4*256*sizeof(float));
  float* fr1 = (float*)take(4*256*sizeof(float));
  float* flF = (float*)take(6*256*sizeof(float));
  float* frF = (float*)take(6*256*sizeof(float));
  size_t need = off;
  (void)aggtl;

  if(ws_size < need){
    k_diag<<<1, 1, 0, stream>>>(out, 100.0f + (float)((double)ws_size / 1073741824.0));
    return;
  }

  // final-phase aliases: aggX [CH][1536] bf16 (76.8MB) over ftres+feat16;
  // partial [6][CH][128] bf16 (38.4MB) over hA16+aggtl-head (both dead then).
  unsigned short* aggX    = ftres;
  unsigned short* partial = hA16;

  // CSR build
  hipMemsetAsync(cur, 0, NN * sizeof(int), stream);
  k_count<<<(NE + 255)/256, 256, 0, stream>>>(dst, cur, NE);
  k_scanA<<<NB, 256, 0, stream>>>(cur, row_ptr, bsum, NN);
  k_scanB<<<1, 256, 0, stream>>>(bsum, boff, NB);
  k_scanC<<<NB, 256, 0, stream>>>(row_ptr, boff, NN, NB);
  hipMemsetAsync(cur, 0, NN * sizeof(int), stream);
  k_scatter<<<(NE + 255)/256, 256, 0, stream>>>(src, dst, row_ptr, cur, col_src, col_dst, NE);

  // converts + folds
  k_cvt<<<(NN*256/4 + 255)/256, 256, 0, stream>>>(features, feat16, NN*256);
  k_cvt3<<<dim3(64, 3), 256, 0, stream>>>(W0, W1, R1, w016, w1r1, w1r1 + 65536, 65536);
  k_cvt2<<<dim3(182, 2), 256, 0, stream>>>(Wf, Rf, wf16, rf16, 185856);
  k_foldAll<<<14, 256, 0, stream>>>(W0, al0, ar0, W1, al1, ar1, Wf, alf, arf,
                                    fl0, fr0, fl1, fr1, flF, frF);

  int gm = (NN + 127) / 128;     // 391
  int gagg = (NN + 3) / 4;       // 12500
  int gedge = (NE + 255) / 256;  // 1563

  // Layer 0: a12(A) -> edge-exp (CSR order) -> GEMM -> agg (writes hA + next a12 into B)
  k_a12dot<4,4><<<gagg, 256, 0, stream>>>(feat16, fl0, fr0, a1A, a2A);
  k_eexp<4><<<gedge, 256, 0, stream>>>(col_src, col_dst, a1A, a2A, ex4);
  k_gemm16<<<dim3(gm, 2), 256, 0, stream>>>(feat16, w016, ftres, NN, 256, 256);
  k_agg4<false,4,4><<<gagg, 256, 0, stream>>>(ftres, 256, ex4, row_ptr, col_src,
      nullptr, 0, hA16, fl1, fr1, a1B, a2B);

  // Layer 1: edge-exp -> fused [W1;R1] GEMM (stride-512) -> agg (writes hB + final a12 into A)
  k_eexp<4><<<gedge, 256, 0, stream>>>(col_src, col_dst, a1B, a2B, ex4);
  k_gemm16<<<dim3(gm, 4), 256, 0, stream>>>(hA16, w1r1, ftres, NN, 512, 512);
  k_agg4<true,6,8><<<gagg, 256, 0, stream>>>(ftres, 512, ex4, row_ptr, col_src,
      ftres + 256, 512, hB16, flF, frF, a1A, a2A);

  // Final layer: edge-exp -> (per chunk) aggregate x -> head-parallel GEMM (BK=64) -> reduce
  k_eexp<8><<<gedge, 256, 0, stream>>>(col_src, col_dst, a1A, a2A, ex6);
  for(int c = 0; c < 2; c++){
    int n0 = c*CH;
    k_aggx6<<<(CH + 3)/4, 256, 0, stream>>>(hB16, ex6, row_ptr, col_src, aggX, n0, CH);
    k_gemmFh<<<dim3((CH + 127)/128, 6), 256, 0, stream>>>(aggX, hB16 + (size_t)n0*256, wf16, rf16, partial, CH);
    k_reduce6<<<(CH*128 + 255)/256, 256, 0, stream>>>(partial, out, n0, CH);
  }
}

// Round 12
// 508.072 us; speedup vs baseline: 1.2526x; 1.0129x over previous
//
#include <hip/hip_runtime.h>
#include <math.h>

#define NN 50000
#define NE 400000
#define NB ((NN + 255) / 256)   // 196 scan blocks

typedef __attribute__((ext_vector_type(8))) short bf16x8;
typedef __attribute__((ext_vector_type(4))) float f32x4;
#define AS1 __attribute__((address_space(1)))
#define AS3 __attribute__((address_space(3)))

__device__ __forceinline__ float lrelu(float x){ return x > 0.0f ? x : 0.01f*x; }
__device__ __forceinline__ float eluf(float x){ return x > 0.0f ? x : __expf(x)-1.0f; }
__device__ __forceinline__ float bf2f(unsigned short u){
  union{unsigned i; float f;} v; v.i = ((unsigned)u)<<16; return v.f;
}
__device__ __forceinline__ unsigned short f2bf(float x){
  union{float f; unsigned i;} v; v.f = x;
  unsigned r = v.i + 0x7FFFu + ((v.i>>16)&1u);
  return (unsigned short)(r>>16);
}
__device__ __forceinline__ unsigned pack2(float a, float b){
  return (unsigned)f2bf(a) | ((unsigned)f2bf(b)<<16);
}
__device__ __forceinline__ float lo16(unsigned u){ return bf2f((unsigned short)(u & 0xffffu)); }
__device__ __forceinline__ float hi16(unsigned u){ return bf2f((unsigned short)(u >> 16)); }

// ---------------- diagnostic ----------------
__global__ void k_diag(float* out, float val){ out[0] = val; }

// ---------------- fp32 -> bf16 convert ----------------
__global__ void k_cvt(const float* __restrict__ in, unsigned short* __restrict__ o, int n){
  int i = (blockIdx.x*256 + threadIdx.x)*4;
  if(i + 3 < n){
    float4 v = *(const float4*)(in + i);
    uint2 p; p.x = pack2(v.x, v.y); p.y = pack2(v.z, v.w);
    *(uint2*)(o + i) = p;
  } else {
    for(int k = i; k < n; k++) o[k] = f2bf(in[k]);
  }
}

__global__ void k_cvt3(const float* __restrict__ s0, const float* __restrict__ s1,
    const float* __restrict__ s2, unsigned short* __restrict__ d0,
    unsigned short* __restrict__ d1, unsigned short* __restrict__ d2, int n){
  const float* in = (blockIdx.y == 0) ? s0 : (blockIdx.y == 1) ? s1 : s2;
  unsigned short* o = (blockIdx.y == 0) ? d0 : (blockIdx.y == 1) ? d1 : d2;
  int i = (blockIdx.x*256 + threadIdx.x)*4;
  if(i + 3 < n){
    float4 v = *(const float4*)(in + i);
    uint2 p; p.x = pack2(v.x, v.y); p.y = pack2(v.z, v.w);
    *(uint2*)(o + i) = p;
  } else {
    for(int k = i; k < n; k++) o[k] = f2bf(in[k]);
  }
}

__global__ void k_cvt2(const float* __restrict__ s0, const float* __restrict__ s1,
    unsigned short* __restrict__ d0, unsigned short* __restrict__ d1, int n){
  const float* in = (blockIdx.y == 0) ? s0 : s1;
  unsigned short* o = (blockIdx.y == 0) ? d0 : d1;
  int i = (blockIdx.x*256 + threadIdx.x)*4;
  if(i + 3 < n){
    float4 v = *(const float4*)(in + i);
    uint2 p; p.x = pack2(v.x, v.y); p.y = pack2(v.z, v.w);
    *(uint2*)(o + i) = p;
  } else {
    for(int k = i; k < n; k++) o[k] = f2bf(in[k]);
  }
}

// ---------------- all folds in one launch ----------------
__global__ void k_foldAll(const float* __restrict__ W0, const float* __restrict__ al0, const float* __restrict__ ar0,
    const float* __restrict__ W1, const float* __restrict__ al1, const float* __restrict__ ar1,
    const float* __restrict__ Wf, const float* __restrict__ alf, const float* __restrict__ arf,
    float* __restrict__ fl0, float* __restrict__ fr0, float* __restrict__ fl1, float* __restrict__ fr1,
    float* __restrict__ flF, float* __restrict__ frF){
  int b = blockIdx.x, d = threadIdx.x;
  const float *W, *al, *ar; float *fl, *fr; int K, h;
  if(b < 4){ W=W0; al=al0; ar=ar0; fl=fl0; fr=fr0; K=64; h=b; }
  else if(b < 8){ W=W1; al=al1; ar=ar1; fl=fl1; fr=fr1; K=64; h=b-4; }
  else { W=Wf; al=alf; ar=arf; fl=flF; fr=frF; K=121; h=b-8; }
  float sl = 0.f, sr = 0.f;
  const float* wb = W + ((size_t)h*K)*256 + d;
  for(int k = 0; k < K; k++){
    float w = wb[(size_t)k*256];
    sl += al[h*K + k]*w;
    sr += ar[h*K + k]*w;
  }
  fl[h*256 + d] = sl;
  fr[h*256 + d] = sr;
}

// ---------------- CSR build ----------------
__global__ void k_count(const int* __restrict__ dst, int* __restrict__ cnt, int E){
  int e = blockIdx.x * 256 + threadIdx.x;
  if(e < E) atomicAdd(&cnt[dst[e]], 1);
}

__global__ void k_scanA(const int* __restrict__ cnt, int* __restrict__ row_ptr,
    int* __restrict__ bsum, int N){
  __shared__ int sh[256];
  int t = threadIdx.x;
  int i = blockIdx.x*256 + t;
  int v = (i < N) ? cnt[i] : 0;
  sh[t] = v;
  __syncthreads();
  for(int off = 1; off < 256; off <<= 1){
    int u = (t >= off) ? sh[t - off] : 0;
    __syncthreads();
    sh[t] += u;
    __syncthreads();
  }
  if(i < N) row_ptr[i] = sh[t] - v;
  if(t == 255) bsum[blockIdx.x] = sh[255];
}

__global__ void k_scanB(const int* __restrict__ bsum, int* __restrict__ boff, int nb){
  __shared__ int sh[256];
  int t = threadIdx.x;
  int v = (t < nb) ? bsum[t] : 0;
  sh[t] = v;
  __syncthreads();
  for(int off = 1; off < 256; off <<= 1){
    int u = (t >= off) ? sh[t - off] : 0;
    __syncthreads();
    sh[t] += u;
    __syncthreads();
  }
  if(t < nb) boff[t] = sh[t] - v;
  if(t == 255) boff[nb] = sh[255];
}

__global__ void k_scanC(int* __restrict__ row_ptr, const int* __restrict__ boff, int N, int nb){
  int i = blockIdx.x*256 + threadIdx.x;
  if(i < N) row_ptr[i] += boff[blockIdx.x];
  if(i == 0) row_ptr[N] = boff[nb];
}

// scatter: also record the dst node per CSR position
__global__ void k_scatter(const int* __restrict__ src, const int* __restrict__ dst,
    const int* __restrict__ row_ptr, int* __restrict__ cur,
    int* __restrict__ col_src, int* __restrict__ col_dst, int E){
  int e = blockIdx.x * 256 + threadIdx.x;
  if(e < E){
    int d = dst[e];
    int pos = row_ptr[d] + atomicAdd(&cur[d], 1);
    col_src[pos] = src[e];
    col_dst[pos] = d;
  }
}

// ---------------- edge-exp precompute (CSR order) ----------------
template<int S>
__global__ __launch_bounds__(256) void k_eexp(const int* __restrict__ col_src, const int* __restrict__ col_dst,
    const float* __restrict__ a1, const float* __restrict__ a2, float* __restrict__ ex){
  int p = blockIdx.x*256 + threadIdx.x;
  if(p >= NE) return;
  int s = col_src[p], d = col_dst[p];
  if(S == 4){
    float4 v1 = *(const float4*)(a1 + (size_t)d*4);
    float4 v2 = *(const float4*)(a2 + (size_t)s*4);
    float4 o;
    o.x = __expf(lrelu(v1.x + v2.x));
    o.y = __expf(lrelu(v1.y + v2.y));
    o.z = __expf(lrelu(v1.z + v2.z));
    o.w = __expf(lrelu(v1.w + v2.w));
    *(float4*)(ex + (size_t)p*4) = o;
  } else {
    float4 l1 = *(const float4*)(a1 + (size_t)d*8);
    float2 h1 = *(const float2*)(a1 + (size_t)d*8 + 4);
    float4 l2 = *(const float4*)(a2 + (size_t)s*8);
    float2 h2 = *(const float2*)(a2 + (size_t)s*8 + 4);
    float4 o;
    o.x = __expf(lrelu(l1.x + l2.x));
    o.y = __expf(lrelu(l1.y + l2.y));
    o.z = __expf(lrelu(l1.z + l2.z));
    o.w = __expf(lrelu(l1.w + l2.w));
    float2 o2;
    o2.x = __expf(lrelu(h1.x + h2.x));
    o2.y = __expf(lrelu(h1.y + h2.y));
    *(float4*)(ex + (size_t)p*8) = o;
    *(float2*)(ex + (size_t)p*8 + 4) = o2;
  }
}

// ---------------- bf16 MFMA GEMM (128x128 tile, BK=64, 4 waves of 64x64) ----------------
__global__ __launch_bounds__(256) void k_gemm16(const unsigned short* __restrict__ X,
    const unsigned short* __restrict__ W, unsigned short* __restrict__ out,
    int N, int Kout, int ostride){
  __shared__ unsigned short sA[8192];   // [slot 8][row 128][8]
  __shared__ unsigned short sB[8192];
  int tid = threadIdx.x;
  int l = tid & 63, w = tid >> 6;
  int wm = w >> 1, wn = w & 1;
  int row0 = blockIdx.x*128, col0 = blockIdx.y*128;

  f32x4 acc[4][4];
  #pragma unroll
  for(int i=0;i<4;i++)
    #pragma unroll
    for(int j=0;j<4;j++) acc[i][j] = (f32x4){0.f,0.f,0.f,0.f};

  int grA0 = row0 + l;        if(grA0 >= N) grA0 = 0;
  int grA1 = row0 + 64 + l;   if(grA1 >= N) grA1 = 0;
  int gcB0 = col0 + l;        if(gcB0 >= Kout) gcB0 = 0;
  int gcB1 = col0 + 64 + l;   if(gcB1 >= Kout) gcB1 = 0;
  const unsigned short* pa0 = X + (size_t)grA0*256 + w*8;
  const unsigned short* pa1 = X + (size_t)grA1*256 + w*8;
  const unsigned short* pb0 = W + (size_t)gcB0*256 + w*8;
  const unsigned short* pb1 = W + (size_t)gcB1*256 + w*8;

  AS3 unsigned short* a3A = (AS3 unsigned short*)sA;
  AS3 unsigned short* a3B = (AS3 unsigned short*)sB;

  #pragma unroll 1
  for(int kt = 0; kt < 256; kt += 64){
    #pragma unroll
    for(int jj = 0; jj < 2; jj++){
      int j = w + jj*4;             // slot
      int ko = kt + jj*32;
      __builtin_amdgcn_global_load_lds((const AS1 void*)(pa0 + ko), (AS3 void*)(a3A + j*1024),       16, 0, 0);
      __builtin_amdgcn_global_load_lds((const AS1 void*)(pa1 + ko), (AS3 void*)(a3A + j*1024 + 512), 16, 0, 0);
      __builtin_amdgcn_global_load_lds((const AS1 void*)(pb0 + ko), (AS3 void*)(a3B + j*1024),       16, 0, 0);
      __builtin_amdgcn_global_load_lds((const AS1 void*)(pb1 + ko), (AS3 void*)(a3B + j*1024 + 512), 16, 0, 0);
    }
    __syncthreads();
    #pragma unroll
    for(int ks = 0; ks < 2; ks++){
      bf16x8 af[4], bfr[4];
      #pragma unroll
      for(int f=0; f<4; f++){
        af[f]  = *(const bf16x8*)(sA + (ks*4 + (l>>4))*1024 + (wm*64 + f*16 + (l&15))*8);
        bfr[f] = *(const bf16x8*)(sB + (ks*4 + (l>>4))*1024 + (wn*64 + f*16 + (l&15))*8);
      }
      #pragma unroll
      for(int i=0;i<4;i++)
        #pragma unroll
        for(int j=0;j<4;j++)
          acc[i][j] = __builtin_amdgcn_mfma_f32_16x16x32_bf16(af[i], bfr[j], acc[i][j], 0, 0, 0);
    }
    __syncthreads();
  }

  #pragma unroll
  for(int i=0;i<4;i++){
    int rbase = row0 + wm*64 + i*16 + (l>>4)*4;
    #pragma unroll
    for(int j=0;j<4;j++){
      int c = col0 + wn*64 + j*16 + (l&15);
      if(c < Kout){
        #pragma unroll
        for(int q=0;q<4;q++){
          int r = rbase + q;
          if(r < N) out[(size_t)r*ostride + c] = f2bf(acc[i][j][q]);
        }
      }
    }
  }
}

// ---------------- final GEMM, one head per block, BK=64; bf16 elu partials ----------------
__global__ __launch_bounds__(256) void k_gemmFh(const unsigned short* __restrict__ aggX,
    const unsigned short* __restrict__ xin, const unsigned short* __restrict__ wf,
    const unsigned short* __restrict__ rf, unsigned short* __restrict__ partial, int M){
  __shared__ unsigned short sA[8192];   // [slot 8][row 128][8]
  __shared__ unsigned short sB[8192];
  int tid = threadIdx.x;
  int l = tid & 63, w = tid >> 6;
  int wm = w >> 1, wn = w & 1;
  int h = blockIdx.y;
  int row0 = blockIdx.x*128;
  int rA0 = row0 + l;      if(rA0 >= M) rA0 = 0;
  int rA1 = row0 + 64 + l; if(rA1 >= M) rA1 = 0;
  int cB1 = 64 + l; if(cB1 > 120) cB1 = 120;

  AS3 unsigned short* a3A = (AS3 unsigned short*)sA;
  AS3 unsigned short* a3B = (AS3 unsigned short*)sB;

  f32x4 acc[4][4];
  #pragma unroll
  for(int i=0;i<4;i++)
    #pragma unroll
    for(int j=0;j<4;j++) acc[i][j] = (f32x4){0.f,0.f,0.f,0.f};

  #pragma unroll 1
  for(int ph = 0; ph < 2; ph++){
    const unsigned short* pa0 = (ph ? xin + (size_t)rA0*256 : aggX + (size_t)rA0*1536 + h*256) + w*8;
    const unsigned short* pa1 = (ph ? xin + (size_t)rA1*256 : aggX + (size_t)rA1*1536 + h*256) + w*8;
    const unsigned short* pbb = (ph ? rf : wf) + (size_t)h*121*256;
    const unsigned short* pb0 = pbb + (size_t)l*256 + w*8;
    const unsigned short* pb1 = pbb + (size_t)cB1*256 + w*8;
    #pragma unroll 1
    for(int kt = 0; kt < 256; kt += 64){
      #pragma unroll
      for(int jj = 0; jj < 2; jj++){
        int j = w + jj*4;             // slot
        int ko = kt + jj*32;
        __builtin_amdgcn_global_load_lds((const AS1 void*)(pa0 + ko), (AS3 void*)(a3A + j*1024),       16, 0, 0);
        __builtin_amdgcn_global_load_lds((const AS1 void*)(pa1 + ko), (AS3 void*)(a3A + j*1024 + 512), 16, 0, 0);
        __builtin_amdgcn_global_load_lds((const AS1 void*)(pb0 + ko), (AS3 void*)(a3B + j*1024),       16, 0, 0);
        __builtin_amdgcn_global_load_lds((const AS1 void*)(pb1 + ko), (AS3 void*)(a3B + j*1024 + 512), 16, 0, 0);
      }
      __syncthreads();
      #pragma unroll
      for(int ks = 0; ks < 2; ks++){
        bf16x8 af[4], bfr[4];
        #pragma unroll
        for(int f=0; f<4; f++){
          af[f]  = *(const bf16x8*)(sA + (ks*4 + (l>>4))*1024 + (wm*64 + f*16 + (l&15))*8);
          bfr[f] = *(const bf16x8*)(sB + (ks*4 + (l>>4))*1024 + (wn*64 + f*16 + (l&15))*8);
        }
        #pragma unroll
        for(int i=0;i<4;i++)
          #pragma unroll
          for(int j=0;j<4;j++)
            acc[i][j] = __builtin_amdgcn_mfma_f32_16x16x32_bf16(af[i], bfr[j], acc[i][j], 0, 0, 0);
      }
      __syncthreads();
    }
  }

  unsigned short* pb = partial + (size_t)h*M*128;
  #pragma unroll
  for(int i=0;i<4;i++){
    int rbase = row0 + wm*64 + i*16 + (l>>4)*4;
    #pragma unroll
    for(int j=0;j<4;j++){
      int c = wn*64 + j*16 + (l&15);
      #pragma unroll
      for(int q=0;q<4;q++){
        int r = rbase + q;
        if(r < M) pb[(size_t)r*128 + c] = f2bf(eluf(acc[i][j][q]));
      }
    }
  }
}

// ---------------- reduce 6 bf16 head partials -> out ----------------
__global__ __launch_bounds__(256) void k_reduce6(const unsigned short* __restrict__ partial,
    float* __restrict__ outp, int n0, int M){
  int t = blockIdx.x*256 + threadIdx.x;
  int idx = t >> 7, c = t & 127;
  if(idx >= M || c >= 121) return;
  float s = 0.f;
  #pragma unroll
  for(int h = 0; h < 6; h++) s += bf2f(partial[((size_t)h*M + idx)*128 + c]);
  outp[(size_t)(n0 + idx)*121 + c] = s * (1.0f/6.0f);
}

// ---------------- folded attention scalars (layer 0 only) ----------------
template<int H, int OS>
__global__ __launch_bounds__(256) void k_a12dot(const unsigned short* __restrict__ x,
    const float* __restrict__ fl, const float* __restrict__ fr,
    float* __restrict__ a1, float* __restrict__ a2){
  int n = blockIdx.x*4 + (threadIdx.x>>6);
  if(n >= NN) return;
  int l = threadIdx.x & 63;
  uint2 rv = *(const uint2*)(x + (size_t)n*256 + l*4);
  float c0 = lo16(rv.x), c1 = hi16(rv.x), c2 = lo16(rv.y), c3 = hi16(rv.y);
  float s1[H], s2[H];
  #pragma unroll
  for(int h = 0; h < H; h++){
    float4 vl = *(const float4*)(fl + h*256 + l*4);
    float4 vr = *(const float4*)(fr + h*256 + l*4);
    s1[h] = c0*vl.x + c1*vl.y + c2*vl.z + c3*vl.w;
    s2[h] = c0*vr.x + c1*vr.y + c2*vr.z + c3*vr.w;
  }
  #pragma unroll
  for(int off = 32; off > 0; off >>= 1){
    #pragma unroll
    for(int h = 0; h < H; h++){
      s1[h] += __shfl_xor(s1[h], off);
      s2[h] += __shfl_xor(s2[h], off);
    }
  }
  if(l == 0){
    #pragma unroll
    for(int h = 0; h < H; h++){ a1[(size_t)n*OS + h] = s1[h]; a2[(size_t)n*OS + h] = s2[h]; }
  }
}

// ---------------- aggregation H=4 K=64: CSR weights, unroll 8/4/1, fused next a12 ----------------
template<bool HAS_RES, int NH, int NOS>
__global__ __launch_bounds__(256) void k_agg4(const unsigned short* __restrict__ ft, int fts,
    const float* __restrict__ ex4,
    const int* __restrict__ row_ptr, const int* __restrict__ col_src,
    const unsigned short* __restrict__ res, int rs, unsigned short* __restrict__ outp,
    const float* __restrict__ nfl, const float* __restrict__ nfr,
    float* __restrict__ na1, float* __restrict__ na2){
  int n = blockIdx.x*4 + (threadIdx.x>>6);
  if(n >= NN) return;
  int l = threadIdx.x & 63;
  int h = l >> 4;
  int e0 = row_ptr[n], e1 = row_ptr[n+1];
  float acc0=0.f, acc1=0.f, acc2=0.f, acc3=0.f, d=0.f;
  int e = e0;
  for(; e + 8 <= e1; e += 8){
    int s0 = col_src[e],   s1 = col_src[e+1], s2 = col_src[e+2], s3 = col_src[e+3];
    int s4 = col_src[e+4], s5 = col_src[e+5], s6 = col_src[e+6], s7 = col_src[e+7];
    uint2 r0 = *(const uint2*)(ft + (size_t)s0*fts + l*4);
    uint2 r1 = *(const uint2*)(ft + (size_t)s1*fts + l*4);
    uint2 r2 = *(const uint2*)(ft + (size_t)s2*fts + l*4);
    uint2 r3 = *(const uint2*)(ft + (size_t)s3*fts + l*4);
    uint2 r4 = *(const uint2*)(ft + (size_t)s4*fts + l*4);
    uint2 r5 = *(const uint2*)(ft + (size_t)s5*fts + l*4);
    uint2 r6 = *(const uint2*)(ft + (size_t)s6*fts + l*4);
    uint2 r7 = *(const uint2*)(ft + (size_t)s7*fts + l*4);
    float x0 = ex4[(size_t)(e+0)*4 + h];
    float x1 = ex4[(size_t)(e+1)*4 + h];
    float x2 = ex4[(size_t)(e+2)*4 + h];
    float x3 = ex4[(size_t)(e+3)*4 + h];
    float x4 = ex4[(size_t)(e+4)*4 + h];
    float x5 = ex4[(size_t)(e+5)*4 + h];
    float x6 = ex4[(size_t)(e+6)*4 + h];
    float x7 = ex4[(size_t)(e+7)*4 + h];
    d += ((x0 + x1) + (x2 + x3)) + ((x4 + x5) + (x6 + x7));
    acc0 += x0*lo16(r0.x) + x1*lo16(r1.x) + x2*lo16(r2.x) + x3*lo16(r3.x)
          + x4*lo16(r4.x) + x5*lo16(r5.x) + x6*lo16(r6.x) + x7*lo16(r7.x);
    acc1 += x0*hi16(r0.x) + x1*hi16(r1.x) + x2*hi16(r2.x) + x3*hi16(r3.x)
          + x4*hi16(r4.x) + x5*hi16(r5.x) + x6*hi16(r6.x) + x7*hi16(r7.x);
    acc2 += x0*lo16(r0.y) + x1*lo16(r1.y) + x2*lo16(r2.y) + x3*lo16(r3.y)
          + x4*lo16(r4.y) + x5*lo16(r5.y) + x6*lo16(r6.y) + x7*lo16(r7.y);
    acc3 += x0*hi16(r0.y) + x1*hi16(r1.y) + x2*hi16(r2.y) + x3*hi16(r3.y)
          + x4*hi16(r4.y) + x5*hi16(r5.y) + x6*hi16(r6.y) + x7*hi16(r7.y);
  }
  for(; e + 4 <= e1; e += 4){
    int s0 = col_src[e], s1 = col_src[e+1], s2 = col_src[e+2], s3 = col_src[e+3];
    uint2 r0 = *(const uint2*)(ft + (size_t)s0*fts + l*4);
    uint2 r1 = *(const uint2*)(ft + (size_t)s1*fts + l*4);
    uint2 r2 = *(const uint2*)(ft + (size_t)s2*fts + l*4);
    uint2 r3 = *(const uint2*)(ft + (size_t)s3*fts + l*4);
    float x0 = ex4[(size_t)(e+0)*4 + h];
    float x1 = ex4[(size_t)(e+1)*4 + h];
    float x2 = ex4[(size_t)(e+2)*4 + h];
    float x3 = ex4[(size_t)(e+3)*4 + h];
    d += (x0 + x1) + (x2 + x3);
    acc0 += x0*lo16(r0.x) + x1*lo16(r1.x) + x2*lo16(r2.x) + x3*lo16(r3.x);
    acc1 += x0*hi16(r0.x) + x1*hi16(r1.x) + x2*hi16(r2.x) + x3*hi16(r3.x);
    acc2 += x0*lo16(r0.y) + x1*lo16(r1.y) + x2*lo16(r2.y) + x3*lo16(r3.y);
    acc3 += x0*hi16(r0.y) + x1*hi16(r1.y) + x2*hi16(r2.y) + x3*hi16(r3.y);
  }
  for(; e < e1; ++e){
    int s = col_src[e];
    float x = ex4[(size_t)e*4 + h];
    d += x;
    uint2 rv = *(const uint2*)(ft + (size_t)s*fts + l*4);
    acc0 += x*lo16(rv.x); acc1 += x*hi16(rv.x);
    acc2 += x*lo16(rv.y); acc3 += x*hi16(rv.y);
  }
  float inv = (e1 > e0) ? 1.0f/d : 0.0f;
  float v0 = acc0*inv, v1 = acc1*inv, v2 = acc2*inv, v3 = acc3*inv;
  if(HAS_RES){
    uint2 rr = *(const uint2*)(res + (size_t)n*rs + l*4);
    v0 += lo16(rr.x); v1 += hi16(rr.x); v2 += lo16(rr.y); v3 += hi16(rr.y);
  }
  float o0 = eluf(v0), o1 = eluf(v1), o2 = eluf(v2), o3 = eluf(v3);
  uint2 o;
  o.x = pack2(o0, o1);
  o.y = pack2(o2, o3);
  *(uint2*)(outp + (size_t)n*256 + l*4) = o;

  // fused a12 for next layer
  float s1[NH], s2[NH];
  #pragma unroll
  for(int hh = 0; hh < NH; hh++){
    float4 vl = *(const float4*)(nfl + hh*256 + l*4);
    float4 vr = *(const float4*)(nfr + hh*256 + l*4);
    s1[hh] = o0*vl.x + o1*vl.y + o2*vl.z + o3*vl.w;
    s2[hh] = o0*vr.x + o1*vr.y + o2*vr.z + o3*vr.w;
  }
  #pragma unroll
  for(int off = 32; off > 0; off >>= 1){
    #pragma unroll
    for(int hh = 0; hh < NH; hh++){
      s1[hh] += __shfl_xor(s1[hh], off);
      s2[hh] += __shfl_xor(s2[hh], off);
    }
  }
  if(l == 0){
    #pragma unroll
    for(int hh = 0; hh < NH; hh++){
      na1[(size_t)n*NOS + hh] = s1[hh];
      na2[(size_t)n*NOS + hh] = s2[hh];
    }
  }
}

// ---------------- final aggregation of x (6 heads), CSR weights, unroll 4/1 ----------------
__global__ __launch_bounds__(256) void k_aggx6(const unsigned short* __restrict__ x,
    const float* __restrict__ ex6,
    const int* __restrict__ row_ptr, const int* __restrict__ col_src,
    unsigned short* __restrict__ aggX, int n0base, int M){
  int idx = blockIdx.x*4 + (threadIdx.x>>6);
  if(idx >= M) return;
  int n = n0base + idx;
  int l = threadIdx.x & 63;
  int e0 = row_ptr[n], e1 = row_ptr[n+1];
  float acc[6][4];
  float d[6];
  #pragma unroll
  for(int h=0;h<6;h++){ d[h]=0.f; acc[h][0]=0.f; acc[h][1]=0.f; acc[h][2]=0.f; acc[h][3]=0.f; }
  int e = e0;
  for(; e + 4 <= e1; e += 4){
    int s0 = col_src[e], s1 = col_src[e+1], s2 = col_src[e+2], s3 = col_src[e+3];
    uint2 rv0 = *(const uint2*)(x + (size_t)s0*256 + l*4);
    uint2 rv1 = *(const uint2*)(x + (size_t)s1*256 + l*4);
    uint2 rv2 = *(const uint2*)(x + (size_t)s2*256 + l*4);
    uint2 rv3 = *(const uint2*)(x + (size_t)s3*256 + l*4);
    float4 xl0 = *(const float4*)(ex6 + (size_t)(e+0)*8);
    float2 xh0 = *(const float2*)(ex6 + (size_t)(e+0)*8 + 4);
    float4 xl1 = *(const float4*)(ex6 + (size_t)(e+1)*8);
    float2 xh1 = *(const float2*)(ex6 + (size_t)(e+1)*8 + 4);
    float4 xl2 = *(const float4*)(ex6 + (size_t)(e+2)*8);
    float2 xh2 = *(const float2*)(ex6 + (size_t)(e+2)*8 + 4);
    float4 xl3 = *(const float4*)(ex6 + (size_t)(e+3)*8);
    float2 xh3 = *(const float2*)(ex6 + (size_t)(e+3)*8 + 4);
    float ex0[6] = {xl0.x, xl0.y, xl0.z, xl0.w, xh0.x, xh0.y};
    float ex1[6] = {xl1.x, xl1.y, xl1.z, xl1.w, xh1.x, xh1.y};
    float ex2[6] = {xl2.x, xl2.y, xl2.z, xl2.w, xh2.x, xh2.y};
    float ex3[6] = {xl3.x, xl3.y, xl3.z, xl3.w, xh3.x, xh3.y};
    float c00 = lo16(rv0.x), c01 = hi16(rv0.x), c02 = lo16(rv0.y), c03 = hi16(rv0.y);
    float c10 = lo16(rv1.x), c11 = hi16(rv1.x), c12 = lo16(rv1.y), c13 = hi16(rv1.y);
    float c20 = lo16(rv2.x), c21 = hi16(rv2.x), c22 = lo16(rv2.y), c23 = hi16(rv2.y);
    float c30 = lo16(rv3.x), c31 = hi16(rv3.x), c32 = lo16(rv3.y), c33 = hi16(rv3.y);
    #pragma unroll
    for(int h=0;h<6;h++){
      d[h] += (ex0[h] + ex1[h]) + (ex2[h] + ex3[h]);
      acc[h][0] += ex0[h]*c00 + ex1[h]*c10 + ex2[h]*c20 + ex3[h]*c30;
      acc[h][1] += ex0[h]*c01 + ex1[h]*c11 + ex2[h]*c21 + ex3[h]*c31;
      acc[h][2] += ex0[h]*c02 + ex1[h]*c12 + ex2[h]*c22 + ex3[h]*c32;
      acc[h][3] += ex0[h]*c03 + ex1[h]*c13 + ex2[h]*c23 + ex3[h]*c33;
    }
  }
  for(; e < e1; ++e){
    int s = col_src[e];
    uint2 rv = *(const uint2*)(x + (size_t)s*256 + l*4);
    float4 xl = *(const float4*)(ex6 + (size_t)e*8);
    float2 xh = *(const float2*)(ex6 + (size_t)e*8 + 4);
    float exv[6] = {xl.x, xl.y, xl.z, xl.w, xh.x, xh.y};
    float c0 = lo16(rv.x), c1 = hi16(rv.x), c2 = lo16(rv.y), c3 = hi16(rv.y);
    #pragma unroll
    for(int h=0;h<6;h++){
      d[h] += exv[h];
      acc[h][0] += exv[h]*c0;
      acc[h][1] += exv[h]*c1;
      acc[h][2] += exv[h]*c2;
      acc[h][3] += exv[h]*c3;
    }
  }
  bool deg = e1 > e0;
  #pragma unroll
  for(int h=0;h<6;h++){
    float inv = deg ? 1.0f/d[h] : 0.0f;
    uint2 o;
    o.x = pack2(acc[h][0]*inv, acc[h][1]*inv);
    o.y = pack2(acc[h][2]*inv, acc[h][3]*inv);
    *(uint2*)(aggX + (size_t)idx*1536 + h*256 + l*4) = o;
  }
}

// ---------------- host ----------------
extern "C" void kernel_launch(void* const* d_in, const int* in_sizes, int n_in,
                              void* d_out, int out_size, void* d_ws, size_t ws_size,
                              hipStream_t stream){
  const float* features = (const float*)d_in[0];
  const int*   src      = (const int*)d_in[1];
  const int*   dst      = (const int*)d_in[2];
  const float* W0  = (const float*)d_in[3];
  const float* al0 = (const float*)d_in[4];
  const float* ar0 = (const float*)d_in[5];
  const float* W1  = (const float*)d_in[6];
  const float* al1 = (const float*)d_in[7];
  const float* ar1 = (const float*)d_in[8];
  const float* R1  = (const float*)d_in[9];
  const float* Wf  = (const float*)d_in[10];
  const float* alf = (const float*)d_in[11];
  const float* arf = (const float*)d_in[12];
  const float* Rf  = (const float*)d_in[13];
  float* out = (float*)d_out;
  (void)in_sizes; (void)n_in; (void)out_size;

  char* ws = (char*)d_ws;
  size_t off = 0;
  auto take = [&](size_t bytes) -> void* {
    void* p = ws + off;
    off += (bytes + 255) & ~(size_t)255;
    return p;
  };
  const int CH = 25000;
  int* row_ptr = (int*)take((NN + 1) * sizeof(int));
  int* cur     = (int*)take(NN * sizeof(int));
  int* col_src = (int*)take(NE * sizeof(int));
  int* col_dst = (int*)take(NE * sizeof(int));
  int* bsum    = (int*)take(256 * sizeof(int));
  int* boff    = (int*)take(257 * sizeof(int));
  float* a1A = (float*)take((size_t)NN * 8 * sizeof(float));
  float* a2A = (float*)take((size_t)NN * 8 * sizeof(float));
  float* a1B = (float*)take((size_t)NN * 8 * sizeof(float));
  float* a2B = (float*)take((size_t)NN * 8 * sizeof(float));
  unsigned short* hB16   = (unsigned short*)take((size_t)NN * 256 * 2);  // 25.6 MB
  unsigned short* ftres  = (unsigned short*)take((size_t)NN * 512 * 2);  // 51.2 MB
  unsigned short* feat16 = (unsigned short*)take((size_t)NN * 256 * 2);  // 25.6 MB
  unsigned short* hA16   = (unsigned short*)take((size_t)NN * 256 * 2);  // 25.6 MB
  unsigned short* aggtl  = (unsigned short*)take((size_t)NN * 512 * 2);  // 51.2 MB
  float* ex4 = (float*)take((size_t)NE * 4 * sizeof(float));             // 6.4 MB
  float* ex6 = (float*)take((size_t)NE * 8 * sizeof(float));             // 12.8 MB
  unsigned short* w016  = (unsigned short*)take(65536 * 2);
  unsigned short* w1r1  = (unsigned short*)take(131072 * 2);
  unsigned short* wf16  = (unsigned short*)take(185856 * 2);
  unsigned short* rf16  = (unsigned short*)take(185856 * 2);
  float* fl0 = (float*)take(4*256*sizeof(float));
  float* fr0 = (float*)take(4*256*sizeof(float));
  float* fl1 = (float*)take(4*256*sizeof(float));
  float* fr1 = (float*)take(4*256*sizeof(float));
  float* flF = (float*)take(6*256*sizeof(float));
  float* frF = (float*)take(6*256*sizeof(float));
  size_t need = off;
  (void)aggtl;

  if(ws_size < need){
    k_diag<<<1, 1, 0, stream>>>(out, 100.0f + (float)((double)ws_size / 1073741824.0));
    return;
  }

  // final-phase aliases: aggX [CH][1536] bf16 (76.8MB) over ftres+feat16;
  // partial [6][CH][128] bf16 (38.4MB) over hA16+aggtl-head (both dead then).
  unsigned short* aggX    = ftres;
  unsigned short* partial = hA16;

  // CSR build
  hipMemsetAsync(cur, 0, NN * sizeof(int), stream);
  k_count<<<(NE + 255)/256, 256, 0, stream>>>(dst, cur, NE);
  k_scanA<<<NB, 256, 0, stream>>>(cur, row_ptr, bsum, NN);
  k_scanB<<<1, 256, 0, stream>>>(bsum, boff, NB);
  k_scanC<<<NB, 256, 0, stream>>>(row_ptr, boff, NN, NB);
  hipMemsetAsync(cur, 0, NN * sizeof(int), stream);
  k_scatter<<<(NE + 255)/256, 256, 0, stream>>>(src, dst, row_ptr, cur, col_src, col_dst, NE);

  // converts + folds
  k_cvt<<<(NN*256/4 + 255)/256, 256, 0, stream>>>(features, feat16, NN*256);
  k_cvt3<<<dim3(64, 3), 256, 0, stream>>>(W0, W1, R1, w016, w1r1, w1r1 + 65536, 65536);
  k_cvt2<<<dim3(182, 2), 256, 0, stream>>>(Wf, Rf, wf16, rf16, 185856);
  k_foldAll<<<14, 256, 0, stream>>>(W0, al0, ar0, W1, al1, ar1, Wf, alf, arf,
                                    fl0, fr0, fl1, fr1, flF, frF);

  int gm = (NN + 127) / 128;     // 391
  int gagg = (NN + 3) / 4;       // 12500
  int gedge = (NE + 255) / 256;  // 1563

  // Layer 0: a12(A) -> edge-exp (CSR order) -> GEMM -> agg (writes hA + next a12 into B)
  k_a12dot<4,4><<<gagg, 256, 0, stream>>>(feat16, fl0, fr0, a1A, a2A);
  k_eexp<4><<<gedge, 256, 0, stream>>>(col_src, col_dst, a1A, a2A, ex4);
  k_gemm16<<<dim3(gm, 2), 256, 0, stream>>>(feat16, w016, ftres, NN, 256, 256);
  k_agg4<false,4,4><<<gagg, 256, 0, stream>>>(ftres, 256, ex4, row_ptr, col_src,
      nullptr, 0, hA16, fl1, fr1, a1B, a2B);

  // Layer 1: edge-exp -> fused [W1;R1] GEMM (stride-512) -> agg (writes hB + final a12 into A)
  k_eexp<4><<<gedge, 256, 0, stream>>>(col_src, col_dst, a1B, a2B, ex4);
  k_gemm16<<<dim3(gm, 4), 256, 0, stream>>>(hA16, w1r1, ftres, NN, 512, 512);
  k_agg4<true,6,8><<<gagg, 256, 0, stream>>>(ftres, 512, ex4, row_ptr, col_src,
      ftres + 256, 512, hB16, flF, frF, a1A, a2A);

  // Final layer: edge-exp -> (per chunk) aggregate x -> head-parallel GEMM (BK=64) -> reduce
  k_eexp<8><<<gedge, 256, 0, stream>>>(col_src, col_dst, a1A, a2A, ex6);
  for(int c = 0; c < 2; c++){
    int n0 = c*CH;
    k_aggx6<<<(CH + 3)/4, 256, 0, stream>>>(hB16, ex6, row_ptr, col_src, aggX, n0, CH);
    k_gemmFh<<<dim3((CH + 127)/128, 6), 256, 0, stream>>>(aggX, hB16 + (size_t)n0*256, wf16, rf16, partial, CH);
    k_reduce6<<<(CH*128 + 255)/256, 256, 0, stream>>>(partial, out, n0, CH);
  }
}